// Round 6
// baseline (3410.345 us; speedup 1.0000x reference)
//
#include <hip/hip_runtime.h>
#include <hip/hip_bf16.h>
#include <hip/hip_fp16.h>
#include <math.h>

#define Mq 50000
#define Hh 32
#define MHt 1600000
#define SLOPE 0.1f

#define GRID_K1 1024
#define GRID_SWEEP 2048

typedef __hip_bfloat16 bf16;

__device__ __forceinline__ float lrelu(float x) { return x >= 0.f ? x : SLOPE * x; }

// 64-wide dot: row is an LDS row base (wave-uniform -> broadcast reads), wc in VGPRs
__device__ __forceinline__ float dot64(const float* row, const float* wc, float acc) {
    #pragma unroll
    for (int k4 = 0; k4 < 16; ++k4) {
        float4 a4 = *reinterpret_cast<const float4*>(&row[k4*4]);
        acc = fmaf(a4.x, wc[4*k4+0], acc);
        acc = fmaf(a4.y, wc[4*k4+1], acc);
        acc = fmaf(a4.z, wc[4*k4+2], acc);
        acc = fmaf(a4.w, wc[4*k4+3], acc);
    }
    return acc;
}

// ---------------- K1: moments of nbrs (analytic bn1 stats) ----------------
__launch_bounds__(256)
__global__ void k1_moments(const float* __restrict__ q_pts, const float* __restrict__ s_pts,
                           const int* __restrict__ inds, float* __restrict__ part1) {
    float a0=0.f,a1=0.f,a2=0.f,q00=0.f,q01=0.f,q02=0.f,q11=0.f,q12=0.f,q22=0.f;
    int tid = blockIdx.x * 256 + threadIdx.x;
    for (int p = tid; p < MHt; p += GRID_K1 * 256) {
        int m = p >> 5;
        int idx = inds[p];
        float d0 = s_pts[idx*3+0] - q_pts[m*3+0];
        float d1 = s_pts[idx*3+1] - q_pts[m*3+1];
        float d2 = s_pts[idx*3+2] - q_pts[m*3+2];
        a0 += d0; a1 += d1; a2 += d2;
        q00 = fmaf(d0,d0,q00); q01 = fmaf(d0,d1,q01); q02 = fmaf(d0,d2,q02);
        q11 = fmaf(d1,d1,q11); q12 = fmaf(d1,d2,q12); q22 = fmaf(d2,d2,q22);
    }
    #pragma unroll
    for (int off = 32; off > 0; off >>= 1) {
        a0 += __shfl_down(a0,off); a1 += __shfl_down(a1,off); a2 += __shfl_down(a2,off);
        q00 += __shfl_down(q00,off); q01 += __shfl_down(q01,off); q02 += __shfl_down(q02,off);
        q11 += __shfl_down(q11,off); q12 += __shfl_down(q12,off); q22 += __shfl_down(q22,off);
    }
    __shared__ float sh[4][12];
    int lane = threadIdx.x & 63, wv = threadIdx.x >> 6;
    if (lane == 0) {
        float* r = sh[wv];
        r[0]=a0; r[1]=a1; r[2]=a2; r[3]=q00; r[4]=q01; r[5]=q02; r[6]=q11; r[7]=q12; r[8]=q22;
    }
    __syncthreads();
    if (threadIdx.x < 9) {
        float s = sh[0][threadIdx.x] + sh[1][threadIdx.x] + sh[2][threadIdx.x] + sh[3][threadIdx.x];
        part1[blockIdx.x * 16 + threadIdx.x] = s;
    }
}

// ---------------- fin1: bn1 scale/shift from moments ----------------
__global__ void kfin1(const float* __restrict__ part1, const float* __restrict__ W1,
                      const float* __restrict__ gam, const float* __restrict__ bet,
                      float* __restrict__ st) {
    __shared__ float shf[64][16];
    __shared__ double shd[9];
    int t = threadIdx.x;            // 1024 threads
    int col = t & 15, sl = t >> 4;
    float acc = 0.f;
    for (int r = sl; r < GRID_K1; r += 64) acc += part1[r*16 + col];
    shf[sl][col] = acc;
    __syncthreads();
    if (t < 9) {
        double s = 0.0;
        for (int i = 0; i < 64; ++i) s += (double)shf[i][t];
        shd[t] = s;
    }
    __syncthreads();
    if (t < 64) {
        double S0=shd[0],S1=shd[1],S2=shd[2],P00=shd[3],P01=shd[4],P02=shd[5],P11=shd[6],P12=shd[7],P22=shd[8];
        double w0 = W1[t], w1 = W1[64+t], w2 = W1[128+t];
        double inv = 1.0 / (double)MHt;
        double mean = (S0*w0 + S1*w1 + S2*w2) * inv;
        double e2 = (P00*w0*w0 + P11*w1*w1 + P22*w2*w2 + 2.0*(P01*w0*w1 + P02*w0*w2 + P12*w1*w2)) * inv;
        double var = e2 - mean*mean;
        double scale = (double)gam[t] / sqrt(var + 1e-5);
        st[t] = (float)scale;
        st[64+t] = (float)((double)bet[t] - mean*scale);
    }
}

// ---------------- finS: bn scale/shift from sum/sumsq partials ----------------
__global__ void kfinS(const float* __restrict__ partS, const float* __restrict__ gam,
                      const float* __restrict__ bet, float* __restrict__ st) {
    __shared__ float shf[8][128];
    __shared__ double shd[128];
    int t = threadIdx.x;             // 1024 threads
    int col = t & 127, sl = t >> 7;
    float acc = 0.f;
    for (int r = sl; r < GRID_SWEEP; r += 8) acc += partS[r*128 + col];
    shf[sl][col] = acc;
    __syncthreads();
    if (t < 128) {
        double s = 0.0;
        #pragma unroll
        for (int i = 0; i < 8; ++i) s += (double)shf[i][t];
        shd[t] = s;
    }
    __syncthreads();
    if (t < 64) {
        double inv = 1.0 / (double)MHt;
        double mean = shd[t] * inv;
        double var = shd[64+t] * inv - mean*mean;
        double scale = (double)gam[t] / sqrt(var + 1e-5);
        st[t] = (float)scale;
        st[64+t] = (float)((double)bet[t] - mean*scale);
    }
}

// ---------------- K2: geom = lrelu(bn1(nbrs@W1))@W2+b2 ; stats of v'=feats-geom ----------------
// Phase-restructured: 32 points (= one m) per block-iter; wave g owns rows g*8..g*8+7.
__launch_bounds__(256)
__global__ void k2_geom(const float* __restrict__ q_pts, const float* __restrict__ s_pts,
                        const float* __restrict__ s_feats, const int* __restrict__ inds,
                        const float* __restrict__ W1, const float* __restrict__ st1,
                        const float* __restrict__ W2, const float* __restrict__ b2,
                        bf16* __restrict__ geom, float* __restrict__ partS) {
    __shared__ float A1s[32*64];
    __shared__ float redS[256], redQ[256];
    const int tid = threadIdx.x, c = tid & 63, g = tid >> 6;
    float wcol[64];
    #pragma unroll
    for (int k = 0; k < 64; ++k) wcol[k] = W2[k*64 + c];
    const float w10 = W1[c], w11 = W1[64+c], w12 = W1[128+c];
    const float sc = st1[c], sf = st1[64+c], bias = b2[c];
    float accS = 0.f, accQ = 0.f;
    #pragma unroll 1
    for (int m = blockIdx.x; m < Mq; m += GRID_SWEEP) {   // chunk == m (32 points)
        const float q0 = q_pts[m*3+0], q1 = q_pts[m*3+1], q2 = q_pts[m*3+2];
        const int p0 = m*32 + g*8;
        float ft[8];
        // Phase A: activations for 8 rows + prefetch s_feats
        #pragma unroll
        for (int i = 0; i < 8; ++i) {
            int idx = inds[p0 + i];
            float d0 = s_pts[idx*3+0] - q0;
            float d1 = s_pts[idx*3+1] - q1;
            float d2 = s_pts[idx*3+2] - q2;
            float x1 = d0*w10; x1 = fmaf(d1,w11,x1); x1 = fmaf(d2,w12,x1);
            A1s[(g*8+i)*64 + c] = lrelu(fmaf(x1, sc, sf));
            ft[i] = s_feats[(size_t)idx*64 + c];
        }
        __syncthreads();
        // Phase B: dot + store + stats (reads own wave's rows)
        #pragma unroll
        for (int i = 0; i < 8; ++i) {
            float gm = dot64(&A1s[(g*8+i)*64], wcol, bias);
            bf16 gb_ = __float2bfloat16(gm);
            geom[(size_t)(p0 + i)*64 + c] = gb_;
            float vp = ft[i] - __bfloat162float(gb_);   // stats on ROUNDED value
            accS += vp; accQ = fmaf(vp, vp, accQ);
        }
    }
    redS[tid] = accS; redQ[tid] = accQ;
    __syncthreads();
    if (tid < 64) {
        partS[blockIdx.x*128 + tid]      = redS[tid]+redS[64+tid]+redS[128+tid]+redS[192+tid];
        partS[blockIdx.x*128 + 64 + tid] = redQ[tid]+redQ[64+tid]+redQ[128+tid]+redQ[192+tid];
    }
}

// ---------------- K3e: v20 = v2[:,0,:] ; stats of q = v20 - geom (all h) ----------------
__launch_bounds__(256)
__global__ void k3e(const float* __restrict__ s_feats, const int* __restrict__ inds,
                    const bf16* __restrict__ geom, const float* __restrict__ st2,
                    const float* __restrict__ W, const float* __restrict__ bW,
                    float* __restrict__ v20, float* __restrict__ partS) {
    __shared__ float Bs[4*64];
    __shared__ float redS[256], redQ[256];
    const int tid = threadIdx.x, c = tid & 63, g = tid >> 6;
    float wcol[64];
    #pragma unroll
    for (int k = 0; k < 64; ++k) wcol[k] = W[k*64 + c];
    const float sc = st2[c], sf = st2[64+c], bias = bW[c];
    float accS = 0.f, accQ = 0.f;
    #pragma unroll 1
    for (int mb = blockIdx.x; mb < Mq/4; mb += GRID_SWEEP) {
        int m = mb*4 + g;
        size_t p0 = (size_t)m*32;
        int idx = inds[p0];
        float gm0 = __bfloat162float(geom[p0*64 + c]);
        float vp = s_feats[(size_t)idx*64 + c] - gm0;
        Bs[g*64 + c] = lrelu(fmaf(vp, sc, sf));
        __syncthreads();
        float v2v = dot64(&Bs[g*64], wcol, bias);
        v20[(size_t)m*64 + c] = v2v;
        #pragma unroll 4
        for (int h = 0; h < 32; ++h) {
            float gm = __bfloat162float(geom[(p0 + h)*64 + c]);
            float qv = v2v - gm;
            accS += qv; accQ = fmaf(qv, qv, accQ);
        }
        __syncthreads();
    }
    redS[tid] = accS; redQ[tid] = accQ;
    __syncthreads();
    if (tid < 64) {
        partS[blockIdx.x*128 + tid]      = redS[tid]+redS[64+tid]+redS[128+tid]+redS[192+tid];
        partS[blockIdx.x*128 + 64 + tid] = redQ[tid]+redQ[64+tid]+redQ[128+tid]+redQ[192+tid];
    }
}

// ---------------- K4e: stats of x2 = lrelu(bn3(v20-geom))@aW1 (phase-restructured) ----------------
__launch_bounds__(256)
__global__ void k4e(const bf16* __restrict__ geom, const float* __restrict__ v20,
                    const float* __restrict__ st3, const float* __restrict__ W,
                    float* __restrict__ partS) {
    __shared__ float As[32*64];
    __shared__ float redS[256], redQ[256];
    const int tid = threadIdx.x, c = tid & 63, g = tid >> 6;
    float wcol[64];
    #pragma unroll
    for (int k = 0; k < 64; ++k) wcol[k] = W[k*64 + c];
    const float sc = st3[c], sf = st3[64+c];
    float accS = 0.f, accQ = 0.f;
    #pragma unroll 1
    for (int m = blockIdx.x; m < Mq; m += GRID_SWEEP) {
        const float v0 = v20[(size_t)m*64 + c];
        const bf16* gp = geom + (size_t)m*2048 + g*512 + c;
        #pragma unroll
        for (int i = 0; i < 8; ++i) {
            float gm = __bfloat162float(gp[i*64]);
            As[(g*8+i)*64 + c] = lrelu(fmaf(v0 - gm, sc, sf));
        }
        __syncthreads();
        #pragma unroll
        for (int i = 0; i < 8; ++i) {
            float x = dot64(&As[(g*8+i)*64], wcol, 0.f);
            accS += x; accQ = fmaf(x, x, accQ);
        }
        __syncthreads();
    }
    redS[tid] = accS; redQ[tid] = accQ;
    __syncthreads();
    if (tid < 64) {
        partS[blockIdx.x*128 + tid]      = redS[tid]+redS[64+tid]+redS[128+tid]+redS[192+tid];
        partS[blockIdx.x*128 + 64 + tid] = redQ[tid]+redQ[64+tid]+redQ[128+tid]+redQ[192+tid];
    }
}

// ---------------- K5w: x2 -> bn4 -> a3 -> softmax -> wnsG (fp16). Phase-restructured ----------------
__launch_bounds__(256)
__global__ void k5w(const bf16* __restrict__ geom, const float* __restrict__ v20,
                    const float* __restrict__ st3, const float* __restrict__ aW1,
                    const float* __restrict__ st4, const float* __restrict__ W2a,
                    const float* __restrict__ b2a, __half* __restrict__ wnsG) {
    __shared__ float As[32*64];
    __shared__ float A2s[32*68];       // padded: phase-C rows hit distinct banks
    __shared__ float Ws[512];
    __shared__ float a3s[256];
    __shared__ float wns_s[256];
    const int tid = threadIdx.x, c = tid & 63, g = tid >> 6;
    float wA[64];
    #pragma unroll
    for (int k = 0; k < 64; ++k) wA[k] = aW1[k*64 + c];
    Ws[tid] = W2a[tid];
    Ws[256 + tid] = W2a[256 + tid];
    const float sc3 = st3[c], sf3 = st3[64+c];
    const float sc4 = st4[c], sf4 = st4[64+c];
    const int ah = tid >> 3, aj = tid & 7;
    const float bj = b2a[aj];
    #pragma unroll 1
    for (int m = blockIdx.x; m < Mq; m += GRID_SWEEP) {
        const float v0 = v20[(size_t)m*64 + c];
        const bf16* gp = geom + (size_t)m*2048 + g*512 + c;
        // Phase A: 8 activation rows per wave (loads overlapped)
        #pragma unroll
        for (int i = 0; i < 8; ++i) {
            float gm = __bfloat162float(gp[i*64]);
            As[(g*8+i)*64 + c] = lrelu(fmaf(v0 - gm, sc3, sf3));
        }
        __syncthreads();
        // Phase B: x2 dot + bn4 activation (own wave's rows)
        #pragma unroll
        for (int i = 0; i < 8; ++i) {
            int h = g*8 + i;
            float x2v = dot64(&As[h*64], wA, 0.f);
            A2s[h*68 + c] = lrelu(fmaf(x2v, sc4, sf4));
        }
        __syncthreads();
        // Phase C: a3[h][j], one (h,j) per thread (256-way parallel)
        {
            float acc = bj;
            #pragma unroll
            for (int k = 0; k < 64; ++k) acc = fmaf(A2s[ah*68 + k], Ws[k*8 + aj], acc);
            a3s[tid] = acc;
        }
        __syncthreads();
        // Phase D: softmax over h per j
        if (tid < 8) {
            int j = tid;
            float mx = -1e30f;
            for (int h = 0; h < 32; ++h) mx = fmaxf(mx, a3s[h*8 + j]);
            float sum = 0.f;
            for (int h = 0; h < 32; ++h) { float e = expf(a3s[h*8 + j] - mx); wns_s[h*8 + j] = e; sum += e; }
            float r = 1.f / sum;
            for (int h = 0; h < 32; ++h) wns_s[h*8 + j] *= r;
        }
        __syncthreads();
        wnsG[(size_t)m*256 + tid] = __float2half(wns_s[tid]);
    }
}

// ---------------- K6w: recompute v2 = lrelu(bn2(feats-geom))@gW+gb ; out = sum_h v2*wns ----------------
__launch_bounds__(256)
__global__ void k6w(const float* __restrict__ s_feats, const int* __restrict__ inds,
                    const bf16* __restrict__ geom, const float* __restrict__ st2,
                    const float* __restrict__ gW, const float* __restrict__ gb,
                    const __half* __restrict__ wnsG, float* __restrict__ out) {
    __shared__ float Bs[32*64];
    __shared__ float wns_s[256];
    __shared__ float red[4][64];
    const int tid = threadIdx.x, c = tid & 63, g = tid >> 6;
    float wG[64];
    #pragma unroll
    for (int k = 0; k < 64; ++k) wG[k] = gW[k*64 + c];
    const float sc2 = st2[c], sf2 = st2[64+c];
    const float gbias = gb[c];
    const int j = c >> 3;
    #pragma unroll 1
    for (int m = blockIdx.x; m < Mq; m += GRID_SWEEP) {
        wns_s[tid] = __half2float(wnsG[(size_t)m*256 + tid]);
        const int p0 = m*32 + g*8;
        const bf16* gp = geom + (size_t)m*2048 + g*512 + c;
        // Phase A: 8 gathered activation rows per wave
        #pragma unroll
        for (int i = 0; i < 8; ++i) {
            int idx = inds[p0 + i];
            float gm = __bfloat162float(gp[i*64]);
            float vp = s_feats[(size_t)idx*64 + c] - gm;
            Bs[(g*8+i)*64 + c] = lrelu(fmaf(vp, sc2, sf2));
        }
        __syncthreads();
        // Phase B: dot + weighted accumulate (own rows; wns indices g*64.. are own wave's too)
        float accO = 0.f;
        #pragma unroll
        for (int i = 0; i < 8; ++i) {
            int h = g*8 + i;
            float v2v = dot64(&Bs[h*64], wG, gbias);
            accO = fmaf(v2v, wns_s[h*8 + j], accO);
        }
        red[g][c] = accO;
        __syncthreads();
        if (tid < 64) out[(size_t)m*64 + tid] = red[0][tid] + red[1][tid] + red[2][tid] + red[3][tid];
    }
}

// =================== TIER E fallback (round-3 k5e, known-working; used only if ws too small) ===================
__launch_bounds__(256)
__global__ void k5e(const float* __restrict__ s_feats, const int* __restrict__ inds,
                    const bf16* __restrict__ geom, const float* __restrict__ v20,
                    const float* __restrict__ st2, const float* __restrict__ gW, const float* __restrict__ gb,
                    const float* __restrict__ st3, const float* __restrict__ aW1,
                    const float* __restrict__ st4, const float* __restrict__ W2a,
                    const float* __restrict__ b2a, float* __restrict__ out) {
    __shared__ float Vt[32][64];
    __shared__ float v0s[64];
    __shared__ float Bs[4][64];
    __shared__ float As[4][64];
    __shared__ float A2s[4][64];
    __shared__ float a3s[32*8];
    __shared__ float wns[32*8];
    __shared__ float Ws[512];
    __shared__ float red[4][64];
    const int tid = threadIdx.x, c = tid & 63, g = tid >> 6;
    float wG[64], wA[64];
    #pragma unroll
    for (int k = 0; k < 64; ++k) { wG[k] = gW[k*64 + c]; wA[k] = aW1[k*64 + c]; }
    Ws[tid] = W2a[tid];
    Ws[256 + tid] = W2a[256 + tid];
    const float sc2 = st2[c], sf2 = st2[64+c];
    const float sc3 = st3[c], sf3 = st3[64+c];
    const float sc4 = st4[c], sf4 = st4[64+c];
    const float gbias = gb[c];
    #pragma unroll 1
    for (int m = blockIdx.x; m < Mq; m += GRID_SWEEP) {
        if (tid < 64) v0s[tid] = v20[(size_t)m*64 + tid];
        __syncthreads();
        #pragma unroll 1
        for (int ci = 0; ci < 8; ++ci) {
            int h = ci*4 + g;
            int p = m*32 + h;
            int idx = inds[p];
            float gmr = __bfloat162float(geom[(size_t)p*64 + c]);
            float vp = s_feats[(size_t)idx*64 + c] - gmr;
            Bs[g][c] = lrelu(fmaf(vp, sc2, sf2));
            float qv = v0s[c] - gmr;
            As[g][c] = lrelu(fmaf(qv, sc3, sf3));
            __syncthreads();
            Vt[h][c] = dot64(Bs[g], wG, gbias);
            float x2v = dot64(As[g], wA, 0.f);
            A2s[g][c] = lrelu(fmaf(x2v, sc4, sf4));
            __syncthreads();
            if (tid < 32) {
                int hh = tid >> 3, jj = tid & 7;
                float acc = b2a[jj];
                #pragma unroll
                for (int k = 0; k < 64; ++k) acc = fmaf(A2s[hh][k], Ws[k*8 + jj], acc);
                a3s[(ci*4 + hh)*8 + jj] = acc;
            }
        }
        __syncthreads();
        if (tid < 8) {
            int jj = tid;
            float mx = -1e30f;
            for (int h = 0; h < 32; ++h) mx = fmaxf(mx, a3s[h*8 + jj]);
            float sum = 0.f;
            for (int h = 0; h < 32; ++h) { float e = expf(a3s[h*8 + jj] - mx); wns[h*8 + jj] = e; sum += e; }
            float r = 1.f / sum;
            for (int h = 0; h < 32; ++h) wns[h*8 + jj] *= r;
        }
        __syncthreads();
        {
            float acc = 0.f;
            int jj = c >> 3;
            #pragma unroll
            for (int hh = 0; hh < 8; ++hh) {
                int h = g*8 + hh;
                acc = fmaf(Vt[h][c], wns[h*8 + jj], acc);
            }
            red[g][c] = acc;
        }
        __syncthreads();
        if (tid < 64) out[(size_t)m*64 + tid] = red[0][tid] + red[1][tid] + red[2][tid] + red[3][tid];
        __syncthreads();
    }
}

extern "C" void kernel_launch(void* const* d_in, const int* in_sizes, int n_in,
                              void* d_out, int out_size, void* d_ws, size_t ws_size,
                              hipStream_t stream) {
    const float* q_pts   = (const float*)d_in[0];
    const float* s_pts   = (const float*)d_in[1];
    const float* s_feats = (const float*)d_in[2];
    const int*   inds    = (const int*)d_in[3];
    const float* dW1 = (const float*)d_in[4];
    const float* dbg = (const float*)d_in[5];
    const float* dbb = (const float*)d_in[6];
    const float* dW2 = (const float*)d_in[7];
    const float* db2 = (const float*)d_in[8];
    const float* gng = (const float*)d_in[9];
    const float* gnb = (const float*)d_in[10];
    const float* gW  = (const float*)d_in[11];
    const float* gb  = (const float*)d_in[12];
    const float* ang = (const float*)d_in[13];
    const float* anb = (const float*)d_in[14];
    const float* aW1 = (const float*)d_in[15];
    const float* abg = (const float*)d_in[16];
    const float* abb = (const float*)d_in[17];
    const float* aW2 = (const float*)d_in[18];
    const float* ab2 = (const float*)d_in[19];
    float* out = (float*)d_out;

    char* ws = (char*)d_ws;
    float* part1 = (float*)ws;                           // 64KB
    float* partS = (float*)(ws + (1<<20));               // 1MB
    float* st1   = (float*)(ws + (2<<20));
    float* st2 = st1 + 128;
    float* st3 = st1 + 256;
    float* st4 = st1 + 384;
    float* v20  = (float*)(ws + (3<<20));                // 12.8MB
    const size_t szG = (size_t)MHt * 64 * 2;             // 204.8MB bf16

    bf16*  geom = (bf16*)(ws + ((size_t)16<<20));
    __half* wnsG = (__half*)(ws + ((size_t)16<<20) + szG);
    const size_t needE2 = ((size_t)16<<20) + szG + (size_t)Mq*256*2;  // ~246.4MB
    const size_t needE  = ((size_t)16<<20) + szG;                     // ~220.8MB

    if (ws_size < needE) return;

    k1_moments<<<GRID_K1, 256, 0, stream>>>(q_pts, s_pts, inds, part1);
    kfin1<<<1, 1024, 0, stream>>>(part1, dW1, dbg, dbb, st1);
    k2_geom<<<GRID_SWEEP, 256, 0, stream>>>(q_pts, s_pts, s_feats, inds, dW1, st1, dW2, db2, geom, partS);
    kfinS<<<1, 1024, 0, stream>>>(partS, gng, gnb, st2);
    k3e<<<GRID_SWEEP, 256, 0, stream>>>(s_feats, inds, geom, st2, gW, gb, v20, partS);
    kfinS<<<1, 1024, 0, stream>>>(partS, ang, anb, st3);
    k4e<<<GRID_SWEEP, 256, 0, stream>>>(geom, v20, st3, aW1, partS);
    kfinS<<<1, 1024, 0, stream>>>(partS, abg, abb, st4);
    if (ws_size >= needE2) {
        k5w<<<GRID_SWEEP, 256, 0, stream>>>(geom, v20, st3, aW1, st4, aW2, ab2, wnsG);
        k6w<<<GRID_SWEEP, 256, 0, stream>>>(s_feats, inds, geom, st2, gW, gb, wnsG, out);
    } else {
        k5e<<<GRID_SWEEP, 256, 0, stream>>>(s_feats, inds, geom, v20, st2, gW, gb,
                                            st3, aW1, st4, aW2, ab2, out);
    }
}

// Round 9
// 995.515 us; speedup vs baseline: 3.4257x; 3.4257x over previous
//
#include <hip/hip_runtime.h>
#include <hip/hip_bf16.h>
#include <hip/hip_fp16.h>
#include <math.h>

#define Mq 50000
#define Hh 32
#define MHt 1600000
#define SLOPE 0.1f

#define GRID_K1 1024
#define GRID_SWEEP 2048

typedef __hip_bfloat16 bf16;
using bf16x8 = __attribute__((ext_vector_type(8))) short;
using f32x4  = __attribute__((ext_vector_type(4))) float;

__device__ __forceinline__ float lrelu(float x) { return x >= 0.f ? x : SLOPE * x; }

__device__ __forceinline__ unsigned short f2bf(float x) {
    union { __hip_bfloat16 b; unsigned short u; } cv;
    cv.b = __float2bfloat16(x);
    return cv.u;
}
__device__ __forceinline__ float bf2f(unsigned short u) {
    union { float f; unsigned int i; } cv;
    cv.i = ((unsigned int)u) << 16;
    return cv.f;
}

// 64-wide fp32 dot (kept for k3e/k6w accuracy-critical paths)
__device__ __forceinline__ float dot64(const float* row, const float* wc, float acc) {
    #pragma unroll
    for (int k4 = 0; k4 < 16; ++k4) {
        float4 a4 = *reinterpret_cast<const float4*>(&row[k4*4]);
        acc = fmaf(a4.x, wc[4*k4+0], acc);
        acc = fmaf(a4.y, wc[4*k4+1], acc);
        acc = fmaf(a4.z, wc[4*k4+2], acc);
        acc = fmaf(a4.w, wc[4*k4+3], acc);
    }
    return acc;
}

// Load W^T A-fragments for D = W^T @ ACT^T scheme.
// wf[t*2+kc] elem j = bf16( W[8*h4 + j + 32*kc][16*t + r] ),  W row-major [64k][64n]
__device__ __forceinline__ void load_wfrags(const float* __restrict__ W, int r, int h4, bf16x8* wf) {
    #pragma unroll
    for (int t = 0; t < 4; ++t) {
        #pragma unroll
        for (int kc = 0; kc < 2; ++kc) {
            bf16x8 v;
            #pragma unroll
            for (int j = 0; j < 8; ++j)
                v[j] = (short)f2bf(W[(8*h4 + j + 32*kc)*64 + 16*t + r]);
            wf[t*2 + kc] = v;
        }
    }
}

// ---------------- K1: moments of nbrs (analytic bn1 stats) ----------------
__launch_bounds__(256)
__global__ void k1_moments(const float* __restrict__ q_pts, const float* __restrict__ s_pts,
                           const int* __restrict__ inds, float* __restrict__ part1) {
    float a0=0.f,a1=0.f,a2=0.f,q00=0.f,q01=0.f,q02=0.f,q11=0.f,q12=0.f,q22=0.f;
    int tid = blockIdx.x * 256 + threadIdx.x;
    for (int p = tid; p < MHt; p += GRID_K1 * 256) {
        int m = p >> 5;
        int idx = inds[p];
        float d0 = s_pts[idx*3+0] - q_pts[m*3+0];
        float d1 = s_pts[idx*3+1] - q_pts[m*3+1];
        float d2 = s_pts[idx*3+2] - q_pts[m*3+2];
        a0 += d0; a1 += d1; a2 += d2;
        q00 = fmaf(d0,d0,q00); q01 = fmaf(d0,d1,q01); q02 = fmaf(d0,d2,q02);
        q11 = fmaf(d1,d1,q11); q12 = fmaf(d1,d2,q12); q22 = fmaf(d2,d2,q22);
    }
    #pragma unroll
    for (int off = 32; off > 0; off >>= 1) {
        a0 += __shfl_down(a0,off); a1 += __shfl_down(a1,off); a2 += __shfl_down(a2,off);
        q00 += __shfl_down(q00,off); q01 += __shfl_down(q01,off); q02 += __shfl_down(q02,off);
        q11 += __shfl_down(q11,off); q12 += __shfl_down(q12,off); q22 += __shfl_down(q22,off);
    }
    __shared__ float sh[4][12];
    int lane = threadIdx.x & 63, wv = threadIdx.x >> 6;
    if (lane == 0) {
        float* r = sh[wv];
        r[0]=a0; r[1]=a1; r[2]=a2; r[3]=q00; r[4]=q01; r[5]=q02; r[6]=q11; r[7]=q12; r[8]=q22;
    }
    __syncthreads();
    if (threadIdx.x < 9) {
        float s = sh[0][threadIdx.x] + sh[1][threadIdx.x] + sh[2][threadIdx.x] + sh[3][threadIdx.x];
        part1[blockIdx.x * 16 + threadIdx.x] = s;
    }
}

// ---------------- fin1 ----------------
__global__ void kfin1(const float* __restrict__ part1, const float* __restrict__ W1,
                      const float* __restrict__ gam, const float* __restrict__ bet,
                      float* __restrict__ st) {
    __shared__ float shf[64][16];
    __shared__ double shd[9];
    int t = threadIdx.x;
    int col = t & 15, sl = t >> 4;
    float acc = 0.f;
    for (int r = sl; r < GRID_K1; r += 64) acc += part1[r*16 + col];
    shf[sl][col] = acc;
    __syncthreads();
    if (t < 9) {
        double s = 0.0;
        for (int i = 0; i < 64; ++i) s += (double)shf[i][t];
        shd[t] = s;
    }
    __syncthreads();
    if (t < 64) {
        double S0=shd[0],S1=shd[1],S2=shd[2],P00=shd[3],P01=shd[4],P02=shd[5],P11=shd[6],P12=shd[7],P22=shd[8];
        double w0 = W1[t], w1 = W1[64+t], w2 = W1[128+t];
        double inv = 1.0 / (double)MHt;
        double mean = (S0*w0 + S1*w1 + S2*w2) * inv;
        double e2 = (P00*w0*w0 + P11*w1*w1 + P22*w2*w2 + 2.0*(P01*w0*w1 + P02*w0*w2 + P12*w1*w2)) * inv;
        double var = e2 - mean*mean;
        double scale = (double)gam[t] / sqrt(var + 1e-5);
        st[t] = (float)scale;
        st[64+t] = (float)((double)bet[t] - mean*scale);
    }
}

// ---------------- finS ----------------
__global__ void kfinS(const float* __restrict__ partS, const float* __restrict__ gam,
                      const float* __restrict__ bet, float* __restrict__ st) {
    __shared__ float shf[8][128];
    __shared__ double shd[128];
    int t = threadIdx.x;
    int col = t & 127, sl = t >> 7;
    float acc = 0.f;
    for (int r = sl; r < GRID_SWEEP; r += 8) acc += partS[r*128 + col];
    shf[sl][col] = acc;
    __syncthreads();
    if (t < 128) {
        double s = 0.0;
        #pragma unroll
        for (int i = 0; i < 8; ++i) s += (double)shf[i][t];
        shd[t] = s;
    }
    __syncthreads();
    if (t < 64) {
        double inv = 1.0 / (double)MHt;
        double mean = shd[t] * inv;
        double var = shd[64+t] * inv - mean*mean;
        double scale = (double)gam[t] / sqrt(var + 1e-5);
        st[t] = (float)scale;
        st[64+t] = (float)((double)bet[t] - mean*scale);
    }
}

// ---------------- K2 (MFMA): geom = lrelu(bn1(nbrs@W1))@W2+b2 ; stats of v'=feats-geom ----------------
__launch_bounds__(256)
__global__ void k2m(const float* __restrict__ q_pts, const float* __restrict__ s_pts,
                    const float* __restrict__ s_feats, const int* __restrict__ inds,
                    const float* __restrict__ W1, const float* __restrict__ st1,
                    const float* __restrict__ W2, const float* __restrict__ b2,
                    unsigned short* __restrict__ geomU, float* __restrict__ partS) {
    __shared__ unsigned short ACTs[64*72];
    __shared__ float redS[16][16], redQ[16][16];
    const int tid = threadIdx.x;
    const int r = tid & 15, h4 = (tid>>4)&3, w = tid>>6;
    const int cp = tid & 31, rr = tid >> 5;
    bf16x8 wf[8];
    load_wfrags(W2, r, h4, wf);
    const float w1a0 = W1[2*cp],   w1a1 = W1[64+2*cp],   w1a2 = W1[128+2*cp];
    const float w1b0 = W1[2*cp+1], w1b1 = W1[64+2*cp+1], w1b2 = W1[128+2*cp+1];
    const float sca = st1[2*cp], scb = st1[2*cp+1];
    const float sfa = st1[64+2*cp], sfb = st1[64+2*cp+1];
    float accS[16], accQ[16];
    #pragma unroll
    for (int s = 0; s < 16; ++s) { accS[s] = 0.f; accQ[s] = 0.f; }
    #pragma unroll 1
    for (int m2 = blockIdx.x; m2 < Mq/2; m2 += GRID_SWEEP) {
        const int m0 = m2*2;
        const int P0 = m0*32;
        const float qa0=q_pts[m0*3+0],qa1=q_pts[m0*3+1],qa2=q_pts[m0*3+2];
        const float qb0=q_pts[m0*3+3],qb1=q_pts[m0*3+4],qb2=q_pts[m0*3+5];
        #pragma unroll
        for (int i = 0; i < 8; ++i) {
            int rrow = rr*8 + i;
            int idx = inds[P0 + rrow];
            float s0 = s_pts[idx*3+0], s1 = s_pts[idx*3+1], s2 = s_pts[idx*3+2];
            float d0, d1, d2;
            if (rrow < 32) { d0=s0-qa0; d1=s1-qa1; d2=s2-qa2; }
            else           { d0=s0-qb0; d1=s1-qb1; d2=s2-qb2; }
            float x1a = fmaf(d2,w1a2, fmaf(d1,w1a1, d0*w1a0));
            float x1b = fmaf(d2,w1b2, fmaf(d1,w1b1, d0*w1b0));
            float a0 = lrelu(fmaf(x1a, sca, sfa));
            float a1 = lrelu(fmaf(x1b, scb, sfb));
            unsigned int pk = (unsigned int)f2bf(a0) | ((unsigned int)f2bf(a1) << 16);
            *(unsigned int*)&ACTs[rrow*72 + 2*cp] = pk;
        }
        __syncthreads();
        bf16x8 af0 = *(const bf16x8*)&ACTs[(16*w + r)*72 + 8*h4];
        bf16x8 af1 = *(const bf16x8*)&ACTs[(16*w + r)*72 + 8*h4 + 32];
        __syncthreads();
        const int Prow = P0 + 16*w + r;
        const int idxr = inds[Prow];
        f32x4 acc[4];
        #pragma unroll
        for (int t = 0; t < 4; ++t) {
            float4 bb = *(const float4*)&b2[16*t + 4*h4];
            f32x4 c; c[0]=bb.x; c[1]=bb.y; c[2]=bb.z; c[3]=bb.w;
            c = __builtin_amdgcn_mfma_f32_16x16x32_bf16(wf[t*2+0], af0, c, 0, 0, 0);
            c = __builtin_amdgcn_mfma_f32_16x16x32_bf16(wf[t*2+1], af1, c, 0, 0, 0);
            acc[t] = c;
        }
        #pragma unroll
        for (int t = 0; t < 4; ++t) {
            unsigned short u0 = f2bf(acc[t][0]);
            unsigned short u1 = f2bf(acc[t][1]);
            unsigned short u2 = f2bf(acc[t][2]);
            unsigned short u3 = f2bf(acc[t][3]);
            ushort4 sv; sv.x=u0; sv.y=u1; sv.z=u2; sv.w=u3;
            *(ushort4*)&geomU[(size_t)Prow*64 + 16*t + 4*h4] = sv;
            float4 fv = *(const float4*)&s_feats[(size_t)idxr*64 + 16*t + 4*h4];
            float vp0 = fv.x - bf2f(u0); accS[t*4+0]+=vp0; accQ[t*4+0]=fmaf(vp0,vp0,accQ[t*4+0]);
            float vp1 = fv.y - bf2f(u1); accS[t*4+1]+=vp1; accQ[t*4+1]=fmaf(vp1,vp1,accQ[t*4+1]);
            float vp2 = fv.z - bf2f(u2); accS[t*4+2]+=vp2; accQ[t*4+2]=fmaf(vp2,vp2,accQ[t*4+2]);
            float vp3 = fv.w - bf2f(u3); accS[t*4+3]+=vp3; accQ[t*4+3]=fmaf(vp3,vp3,accQ[t*4+3]);
        }
    }
    #pragma unroll
    for (int s = 0; s < 16; ++s) {
        #pragma unroll
        for (int msk = 1; msk <= 8; msk <<= 1) {
            accS[s] += __shfl_xor(accS[s], msk);
            accQ[s] += __shfl_xor(accQ[s], msk);
        }
    }
    if (r == 0) {
        #pragma unroll
        for (int s = 0; s < 16; ++s) { redS[w*4+h4][s] = accS[s]; redQ[w*4+h4][s] = accQ[s]; }
    }
    __syncthreads();
    if (tid < 64) {
        int t = tid >> 4, hh = (tid >> 2) & 3, reg = tid & 3, s = t*4 + reg;
        float aS = 0.f, aQ = 0.f;
        #pragma unroll
        for (int ww = 0; ww < 4; ++ww) { aS += redS[ww*4+hh][s]; aQ += redQ[ww*4+hh][s]; }
        partS[blockIdx.x*128 + tid] = aS;
        partS[blockIdx.x*128 + 64 + tid] = aQ;
    }
}

// ---------------- K3e: v20 = v2[:,0,:] ; stats of q = v20 - geom (all h) ----------------
__launch_bounds__(256)
__global__ void k3e(const float* __restrict__ s_feats, const int* __restrict__ inds,
                    const bf16* __restrict__ geom, const float* __restrict__ st2,
                    const float* __restrict__ W, const float* __restrict__ bW,
                    float* __restrict__ v20, float* __restrict__ partS) {
    __shared__ float Bs[4*64];
    __shared__ float redS[256], redQ[256];
    const int tid = threadIdx.x, c = tid & 63, g = tid >> 6;
    float wcol[64];
    #pragma unroll
    for (int k = 0; k < 64; ++k) wcol[k] = W[k*64 + c];
    const float sc = st2[c], sf = st2[64+c], bias = bW[c];
    float accS = 0.f, accQ = 0.f;
    #pragma unroll 1
    for (int mb = blockIdx.x; mb < Mq/4; mb += GRID_SWEEP) {
        int m = mb*4 + g;
        size_t p0 = (size_t)m*32;
        int idx = inds[p0];
        float gm0 = __bfloat162float(geom[p0*64 + c]);
        float vp = s_feats[(size_t)idx*64 + c] - gm0;
        Bs[g*64 + c] = lrelu(fmaf(vp, sc, sf));
        __syncthreads();
        float v2v = dot64(&Bs[g*64], wcol, bias);
        v20[(size_t)m*64 + c] = v2v;
        #pragma unroll 4
        for (int h = 0; h < 32; ++h) {
            float gm = __bfloat162float(geom[(p0 + h)*64 + c]);
            float qv = v2v - gm;
            accS += qv; accQ = fmaf(qv, qv, accQ);
        }
        __syncthreads();
    }
    redS[tid] = accS; redQ[tid] = accQ;
    __syncthreads();
    if (tid < 64) {
        partS[blockIdx.x*128 + tid]      = redS[tid]+redS[64+tid]+redS[128+tid]+redS[192+tid];
        partS[blockIdx.x*128 + 64 + tid] = redQ[tid]+redQ[64+tid]+redQ[128+tid]+redQ[192+tid];
    }
}

// ---------------- K4 (MFMA): stats of x2 = lrelu(bn3(v20-geom))@aW1 ----------------
__launch_bounds__(256)
__global__ void k4m(const unsigned short* __restrict__ geomU, const float* __restrict__ v20,
                    const float* __restrict__ st3, const float* __restrict__ W,
                    float* __restrict__ partS) {
    __shared__ unsigned short ACTs[64*72];
    __shared__ float redS[16][16], redQ[16][16];
    const int tid = threadIdx.x;
    const int r = tid & 15, h4 = (tid>>4)&3, w = tid>>6;
    const int cp = tid & 31, rr = tid >> 5;
    bf16x8 wf[8];
    load_wfrags(W, r, h4, wf);
    const float sca = st3[2*cp], scb = st3[2*cp+1];
    const float sfa = st3[64+2*cp], sfb = st3[64+2*cp+1];
    float accS[16], accQ[16];
    #pragma unroll
    for (int s = 0; s < 16; ++s) { accS[s] = 0.f; accQ[s] = 0.f; }
    #pragma unroll 1
    for (int m2 = blockIdx.x; m2 < Mq/2; m2 += GRID_SWEEP) {
        const int m0 = m2*2;
        const int P0 = m0*32;
        float2 vA = *(const float2*)&v20[(size_t)m0*64 + 2*cp];
        float2 vB = *(const float2*)&v20[(size_t)(m0+1)*64 + 2*cp];
        #pragma unroll
        for (int i = 0; i < 8; ++i) {
            int rrow = rr*8 + i;
            unsigned int gv = *(const unsigned int*)&geomU[(size_t)(P0+rrow)*64 + 2*cp];
            float g0 = bf2f((unsigned short)(gv & 0xffff));
            float g1 = bf2f((unsigned short)(gv >> 16));
            float v0 = (rrow < 32) ? vA.x : vB.x;
            float v1 = (rrow < 32) ? vA.y : vB.y;
            float a0 = lrelu(fmaf(v0 - g0, sca, sfa));
            float a1 = lrelu(fmaf(v1 - g1, scb, sfb));
            unsigned int pk = (unsigned int)f2bf(a0) | ((unsigned int)f2bf(a1) << 16);
            *(unsigned int*)&ACTs[rrow*72 + 2*cp] = pk;
        }
        __syncthreads();
        bf16x8 af0 = *(const bf16x8*)&ACTs[(16*w + r)*72 + 8*h4];
        bf16x8 af1 = *(const bf16x8*)&ACTs[(16*w + r)*72 + 8*h4 + 32];
        __syncthreads();
        f32x4 acc[4];
        #pragma unroll
        for (int t = 0; t < 4; ++t) {
            f32x4 c = {0.f, 0.f, 0.f, 0.f};
            c = __builtin_amdgcn_mfma_f32_16x16x32_bf16(wf[t*2+0], af0, c, 0, 0, 0);
            c = __builtin_amdgcn_mfma_f32_16x16x32_bf16(wf[t*2+1], af1, c, 0, 0, 0);
            acc[t] = c;
        }
        #pragma unroll
        for (int t = 0; t < 4; ++t) {
            #pragma unroll
            for (int reg = 0; reg < 4; ++reg) {
                float x = acc[t][reg];
                accS[t*4+reg] += x;
                accQ[t*4+reg] = fmaf(x, x, accQ[t*4+reg]);
            }
        }
    }
    #pragma unroll
    for (int s = 0; s < 16; ++s) {
        #pragma unroll
        for (int msk = 1; msk <= 8; msk <<= 1) {
            accS[s] += __shfl_xor(accS[s], msk);
            accQ[s] += __shfl_xor(accQ[s], msk);
        }
    }
    if (r == 0) {
        #pragma unroll
        for (int s = 0; s < 16; ++s) { redS[w*4+h4][s] = accS[s]; redQ[w*4+h4][s] = accQ[s]; }
    }
    __syncthreads();
    if (tid < 64) {
        int t = tid >> 4, hh = (tid >> 2) & 3, reg = tid & 3, s = t*4 + reg;
        float aS = 0.f, aQ = 0.f;
        #pragma unroll
        for (int ww = 0; ww < 4; ++ww) { aS += redS[ww*4+hh][s]; aQ += redQ[ww*4+hh][s]; }
        partS[blockIdx.x*128 + tid] = aS;
        partS[blockIdx.x*128 + 64 + tid] = aQ;
    }
}

// ---------------- K5 (MFMA): x2 -> bn4 -> a3 -> softmax -> wnsG ----------------
__launch_bounds__(256)
__global__ void k5wm(const unsigned short* __restrict__ geomU, const float* __restrict__ v20,
                     const float* __restrict__ st3, const float* __restrict__ aW1,
                     const float* __restrict__ st4, const float* __restrict__ W2a,
                     const float* __restrict__ b2a, __half* __restrict__ wnsG) {
    __shared__ unsigned short ACTs[64*72];
    __shared__ float Ws[512];
    __shared__ float st4s[128];
    __shared__ float b2s[8];
    __shared__ float a3s[2*32*8];
    __shared__ float wns_s[2*256];
    const int tid = threadIdx.x;
    const int r = tid & 15, h4 = (tid>>4)&3, w = tid>>6;
    const int cp = tid & 31, rr = tid >> 5;
    bf16x8 wf[8];
    load_wfrags(aW1, r, h4, wf);
    Ws[tid] = W2a[tid];
    Ws[256 + tid] = W2a[256 + tid];
    if (tid < 128) st4s[tid] = st4[tid];
    if (tid < 8) b2s[tid] = b2a[tid];
    const float sca = st3[2*cp], scb = st3[2*cp+1];
    const float sfa = st3[64+2*cp], sfb = st3[64+2*cp+1];
    __syncthreads();
    #pragma unroll 1
    for (int m2 = blockIdx.x; m2 < Mq/2; m2 += GRID_SWEEP) {
        const int m0 = m2*2;
        const int P0 = m0*32;
        float2 vA = *(const float2*)&v20[(size_t)m0*64 + 2*cp];
        float2 vB = *(const float2*)&v20[(size_t)(m0+1)*64 + 2*cp];
        #pragma unroll
        for (int i = 0; i < 8; ++i) {
            int rrow = rr*8 + i;
            unsigned int gv = *(const unsigned int*)&geomU[(size_t)(P0+rrow)*64 + 2*cp];
            float g0 = bf2f((unsigned short)(gv & 0xffff));
            float g1 = bf2f((unsigned short)(gv >> 16));
            float v0 = (rrow < 32) ? vA.x : vB.x;
            float v1 = (rrow < 32) ? vA.y : vB.y;
            float a0 = lrelu(fmaf(v0 - g0, sca, sfa));
            float a1 = lrelu(fmaf(v1 - g1, scb, sfb));
            unsigned int pk = (unsigned int)f2bf(a0) | ((unsigned int)f2bf(a1) << 16);
            *(unsigned int*)&ACTs[rrow*72 + 2*cp] = pk;
        }
        __syncthreads();
        bf16x8 af0 = *(const bf16x8*)&ACTs[(16*w + r)*72 + 8*h4];
        bf16x8 af1 = *(const bf16x8*)&ACTs[(16*w + r)*72 + 8*h4 + 32];
        __syncthreads();
        f32x4 acc[4];
        #pragma unroll
        for (int t = 0; t < 4; ++t) {
            f32x4 c = {0.f, 0.f, 0.f, 0.f};
            c = __builtin_amdgcn_mfma_f32_16x16x32_bf16(wf[t*2+0], af0, c, 0, 0, 0);
            c = __builtin_amdgcn_mfma_f32_16x16x32_bf16(wf[t*2+1], af1, c, 0, 0, 0);
            acc[t] = c;
        }
        // bn4 + a3 partials over this lane's 16 channels
        float pa3[8];
        #pragma unroll
        for (int j = 0; j < 8; ++j) pa3[j] = 0.f;
        #pragma unroll
        for (int t = 0; t < 4; ++t) {
            #pragma unroll
            for (int reg = 0; reg < 4; ++reg) {
                int ch = 16*t + 4*h4 + reg;
                float a2 = lrelu(fmaf(acc[t][reg], st4s[ch], st4s[64+ch]));
                float4 w0 = *(const float4*)&Ws[ch*8];
                float4 w1 = *(const float4*)&Ws[ch*8 + 4];
                pa3[0] = fmaf(a2, w0.x, pa3[0]);
                pa3[1] = fmaf(a2, w0.y, pa3[1]);
                pa3[2] = fmaf(a2, w0.z, pa3[2]);
                pa3[3] = fmaf(a2, w0.w, pa3[3]);
                pa3[4] = fmaf(a2, w1.x, pa3[4]);
                pa3[5] = fmaf(a2, w1.y, pa3[5]);
                pa3[6] = fmaf(a2, w1.z, pa3[6]);
                pa3[7] = fmaf(a2, w1.w, pa3[7]);
            }
        }
        #pragma unroll
        for (int j = 0; j < 8; ++j) {
            pa3[j] += __shfl_xor(pa3[j], 16);
            pa3[j] += __shfl_xor(pa3[j], 32);
        }
        if ((tid & 63) < 16) {
            int pt = w >> 1, hrow = (w & 1)*16 + r;
            #pragma unroll
            for (int j = 0; j < 8; ++j) a3s[pt*256 + hrow*8 + j] = pa3[j] + b2s[j];
        }
        __syncthreads();
        if (tid < 16) {
            int pt = tid >> 3, j = tid & 7;
            float mx = -1e30f;
            for (int h = 0; h < 32; ++h) mx = fmaxf(mx, a3s[pt*256 + h*8 + j]);
            float sum = 0.f;
            for (int h = 0; h < 32; ++h) {
                float e = expf(a3s[pt*256 + h*8 + j] - mx);
                wns_s[pt*256 + h*8 + j] = e; sum += e;
            }
            float rcp = 1.f / sum;
            for (int h = 0; h < 32; ++h) wns_s[pt*256 + h*8 + j] *= rcp;
        }
        __syncthreads();
        {
            int u = tid*2, pt = u >> 8, off = u & 255;
            __half2 hv;
            hv.x = __float2half(wns_s[pt*256 + off]);
            hv.y = __float2half(wns_s[pt*256 + off + 1]);
            *(__half2*)&wnsG[(size_t)(m0 + pt)*256 + off] = hv;
        }
    }
}

// ---------------- K6w (fp32 VALU, accuracy-critical): v2 recompute + weighted sum ----------------
__launch_bounds__(256)
__global__ void k6w(const float* __restrict__ s_feats, const int* __restrict__ inds,
                    const bf16* __restrict__ geom, const float* __restrict__ st2,
                    const float* __restrict__ gW, const float* __restrict__ gb,
                    const __half* __restrict__ wnsG, float* __restrict__ out) {
    __shared__ float Bs[32*64];
    __shared__ float wns_s[256];
    __shared__ float red[4][64];
    const int tid = threadIdx.x, c = tid & 63, g = tid >> 6;
    float wG[64];
    #pragma unroll
    for (int k = 0; k < 64; ++k) wG[k] = gW[k*64 + c];
    const float sc2 = st2[c], sf2 = st2[64+c];
    const float gbias = gb[c];
    const int j = c >> 3;
    #pragma unroll 1
    for (int m = blockIdx.x; m < Mq; m += GRID_SWEEP) {
        wns_s[tid] = __half2float(wnsG[(size_t)m*256 + tid]);
        const int p0 = m*32 + g*8;
        const bf16* gp = geom + (size_t)m*2048 + g*512 + c;
        #pragma unroll
        for (int i = 0; i < 8; ++i) {
            int idx = inds[p0 + i];
            float gm = __bfloat162float(gp[i*64]);
            float vp = s_feats[(size_t)idx*64 + c] - gm;
            Bs[(g*8+i)*64 + c] = lrelu(fmaf(vp, sc2, sf2));
        }
        __syncthreads();
        float accO = 0.f;
        #pragma unroll
        for (int i = 0; i < 8; ++i) {
            int h = g*8 + i;
            float v2v = dot64(&Bs[h*64], wG, gbias);
            accO = fmaf(v2v, wns_s[h*8 + j], accO);
        }
        red[g][c] = accO;
        __syncthreads();
        if (tid < 64) out[(size_t)m*64 + tid] = red[0][tid] + red[1][tid] + red[2][tid] + red[3][tid];
    }
}

extern "C" void kernel_launch(void* const* d_in, const int* in_sizes, int n_in,
                              void* d_out, int out_size, void* d_ws, size_t ws_size,
                              hipStream_t stream) {
    const float* q_pts   = (const float*)d_in[0];
    const float* s_pts   = (const float*)d_in[1];
    const float* s_feats = (const float*)d_in[2];
    const int*   inds    = (const int*)d_in[3];
    const float* dW1 = (const float*)d_in[4];
    const float* dbg = (const float*)d_in[5];
    const float* dbb = (const float*)d_in[6];
    const float* dW2 = (const float*)d_in[7];
    const float* db2 = (const float*)d_in[8];
    const float* gng = (const float*)d_in[9];
    const float* gnb = (const float*)d_in[10];
    const float* gW  = (const float*)d_in[11];
    const float* gb  = (const float*)d_in[12];
    const float* ang = (const float*)d_in[13];
    const float* anb = (const float*)d_in[14];
    const float* aW1 = (const float*)d_in[15];
    const float* abg = (const float*)d_in[16];
    const float* abb = (const float*)d_in[17];
    const float* aW2 = (const float*)d_in[18];
    const float* ab2 = (const float*)d_in[19];
    float* out = (float*)d_out;

    char* ws = (char*)d_ws;
    float* part1 = (float*)ws;                           // 64KB
    float* partS = (float*)(ws + (1<<20));               // 1MB
    float* st1   = (float*)(ws + (2<<20));
    float* st2 = st1 + 128;
    float* st3 = st1 + 256;
    float* st4 = st1 + 384;
    float* v20  = (float*)(ws + (3<<20));                // 12.8MB
    const size_t szG = (size_t)MHt * 64 * 2;             // 204.8MB bf16

    bf16*  geom = (bf16*)(ws + ((size_t)16<<20));
    unsigned short* geomU = (unsigned short*)geom;
    __half* wnsG = (__half*)(ws + ((size_t)16<<20) + szG);
    const size_t needE2 = ((size_t)16<<20) + szG + (size_t)Mq*256*2;  // ~246.4MB (validated present in r5/r6)

    if (ws_size < needE2) return;

    k1_moments<<<GRID_K1, 256, 0, stream>>>(q_pts, s_pts, inds, part1);
    kfin1<<<1, 1024, 0, stream>>>(part1, dW1, dbg, dbb, st1);
    k2m<<<GRID_SWEEP, 256, 0, stream>>>(q_pts, s_pts, s_feats, inds, dW1, st1, dW2, db2, geomU, partS);
    kfinS<<<1, 1024, 0, stream>>>(partS, gng, gnb, st2);
    k3e<<<GRID_SWEEP, 256, 0, stream>>>(s_feats, inds, geom, st2, gW, gb, v20, partS);
    kfinS<<<1, 1024, 0, stream>>>(partS, ang, anb, st3);
    k4m<<<GRID_SWEEP, 256, 0, stream>>>(geomU, v20, st3, aW1, partS);
    kfinS<<<1, 1024, 0, stream>>>(partS, abg, abb, st4);
    k5wm<<<GRID_SWEEP, 256, 0, stream>>>(geomU, v20, st3, aW1, st4, aW2, ab2, wnsG);
    k6w<<<GRID_SWEEP, 256, 0, stream>>>(s_feats, inds, geom, st2, gW, gb, wnsG, out);
}

// Round 11
// 840.264 us; speedup vs baseline: 4.0587x; 1.1848x over previous
//
#include <hip/hip_runtime.h>
#include <hip/hip_bf16.h>
#include <hip/hip_fp16.h>
#include <math.h>

#define Mq 50000
#define Hh 32
#define MHt 1600000
#define SLOPE 0.1f

#define GRID_K1 1024
#define GRID_SWEEP 2048

typedef __hip_bfloat16 bf16;
using bf16x8 = __attribute__((ext_vector_type(8))) short;
using f32x4  = __attribute__((ext_vector_type(4))) float;

__device__ __forceinline__ float lrelu(float x) { return x >= 0.f ? x : SLOPE * x; }

__device__ __forceinline__ unsigned short f2bf(float x) {
    union { __hip_bfloat16 b; unsigned short u; } cv;
    cv.b = __float2bfloat16(x);
    return cv.u;
}
__device__ __forceinline__ float bf2f(unsigned short u) {
    union { float f; unsigned int i; } cv;
    cv.i = ((unsigned int)u) << 16;
    return cv.f;
}

// 64-wide fp32 dot (k3e only)
__device__ __forceinline__ float dot64(const float* row, const float* wc, float acc) {
    #pragma unroll
    for (int k4 = 0; k4 < 16; ++k4) {
        float4 a4 = *reinterpret_cast<const float4*>(&row[k4*4]);
        acc = fmaf(a4.x, wc[4*k4+0], acc);
        acc = fmaf(a4.y, wc[4*k4+1], acc);
        acc = fmaf(a4.z, wc[4*k4+2], acc);
        acc = fmaf(a4.w, wc[4*k4+3], acc);
    }
    return acc;
}

// Load W^T A-fragments for D = W^T @ ACT^T scheme.
// wf[t*2+kc] elem j = bf16( W[8*h4 + j + 32*kc][16*t + r] ),  W row-major [64k][64n]
__device__ __forceinline__ void load_wfrags(const float* __restrict__ W, int r, int h4, bf16x8* wf) {
    #pragma unroll
    for (int t = 0; t < 4; ++t) {
        #pragma unroll
        for (int kc = 0; kc < 2; ++kc) {
            bf16x8 v;
            #pragma unroll
            for (int j = 0; j < 8; ++j)
                v[j] = (short)f2bf(W[(8*h4 + j + 32*kc)*64 + 16*t + r]);
            wf[t*2 + kc] = v;
        }
    }
}

// ---------------- K1: moments of nbrs (analytic bn1 stats) ----------------
__launch_bounds__(256)
__global__ void k1_moments(const float* __restrict__ q_pts, const float* __restrict__ s_pts,
                           const int* __restrict__ inds, float* __restrict__ part1) {
    float a0=0.f,a1=0.f,a2=0.f,q00=0.f,q01=0.f,q02=0.f,q11=0.f,q12=0.f,q22=0.f;
    int tid = blockIdx.x * 256 + threadIdx.x;
    for (int p = tid; p < MHt; p += GRID_K1 * 256) {
        int m = p >> 5;
        int idx = inds[p];
        float d0 = s_pts[idx*3+0] - q_pts[m*3+0];
        float d1 = s_pts[idx*3+1] - q_pts[m*3+1];
        float d2 = s_pts[idx*3+2] - q_pts[m*3+2];
        a0 += d0; a1 += d1; a2 += d2;
        q00 = fmaf(d0,d0,q00); q01 = fmaf(d0,d1,q01); q02 = fmaf(d0,d2,q02);
        q11 = fmaf(d1,d1,q11); q12 = fmaf(d1,d2,q12); q22 = fmaf(d2,d2,q22);
    }
    #pragma unroll
    for (int off = 32; off > 0; off >>= 1) {
        a0 += __shfl_down(a0,off); a1 += __shfl_down(a1,off); a2 += __shfl_down(a2,off);
        q00 += __shfl_down(q00,off); q01 += __shfl_down(q01,off); q02 += __shfl_down(q02,off);
        q11 += __shfl_down(q11,off); q12 += __shfl_down(q12,off); q22 += __shfl_down(q22,off);
    }
    __shared__ float sh[4][12];
    int lane = threadIdx.x & 63, wv = threadIdx.x >> 6;
    if (lane == 0) {
        float* r = sh[wv];
        r[0]=a0; r[1]=a1; r[2]=a2; r[3]=q00; r[4]=q01; r[5]=q02; r[6]=q11; r[7]=q12; r[8]=q22;
    }
    __syncthreads();
    if (threadIdx.x < 9) {
        float s = sh[0][threadIdx.x] + sh[1][threadIdx.x] + sh[2][threadIdx.x] + sh[3][threadIdx.x];
        part1[blockIdx.x * 16 + threadIdx.x] = s;
    }
}

// ---------------- fin1 ----------------
__global__ void kfin1(const float* __restrict__ part1, const float* __restrict__ W1,
                      const float* __restrict__ gam, const float* __restrict__ bet,
                      float* __restrict__ st) {
    __shared__ float shf[64][16];
    __shared__ double shd[9];
    int t = threadIdx.x;
    int col = t & 15, sl = t >> 4;
    float acc = 0.f;
    for (int r = sl; r < GRID_K1; r += 64) acc += part1[r*16 + col];
    shf[sl][col] = acc;
    __syncthreads();
    if (t < 9) {
        double s = 0.0;
        for (int i = 0; i < 64; ++i) s += (double)shf[i][t];
        shd[t] = s;
    }
    __syncthreads();
    if (t < 64) {
        double S0=shd[0],S1=shd[1],S2=shd[2],P00=shd[3],P01=shd[4],P02=shd[5],P11=shd[6],P12=shd[7],P22=shd[8];
        double w0 = W1[t], w1 = W1[64+t], w2 = W1[128+t];
        double inv = 1.0 / (double)MHt;
        double mean = (S0*w0 + S1*w1 + S2*w2) * inv;
        double e2 = (P00*w0*w0 + P11*w1*w1 + P22*w2*w2 + 2.0*(P01*w0*w1 + P02*w0*w2 + P12*w1*w2)) * inv;
        double var = e2 - mean*mean;
        double scale = (double)gam[t] / sqrt(var + 1e-5);
        st[t] = (float)scale;
        st[64+t] = (float)((double)bet[t] - mean*scale);
    }
}

// ---------------- finS ----------------
__global__ void kfinS(const float* __restrict__ partS, const float* __restrict__ gam,
                      const float* __restrict__ bet, float* __restrict__ st) {
    __shared__ float shf[8][128];
    __shared__ double shd[128];
    int t = threadIdx.x;
    int col = t & 127, sl = t >> 7;
    float acc = 0.f;
    for (int r = sl; r < GRID_SWEEP; r += 8) acc += partS[r*128 + col];
    shf[sl][col] = acc;
    __syncthreads();
    if (t < 128) {
        double s = 0.0;
        #pragma unroll
        for (int i = 0; i < 8; ++i) s += (double)shf[i][t];
        shd[t] = s;
    }
    __syncthreads();
    if (t < 64) {
        double inv = 1.0 / (double)MHt;
        double mean = shd[t] * inv;
        double var = shd[64+t] * inv - mean*mean;
        double scale = (double)gam[t] / sqrt(var + 1e-5);
        st[t] = (float)scale;
        st[64+t] = (float)((double)bet[t] - mean*scale);
    }
}

// ---------------- K2 (MFMA): geom = lrelu(bn1(nbrs@W1))@W2+b2 ; stats of v'=feats-geom ----------------
__launch_bounds__(256)
__global__ void k2m(const float* __restrict__ q_pts, const float* __restrict__ s_pts,
                    const float* __restrict__ s_feats, const int* __restrict__ inds,
                    const float* __restrict__ W1, const float* __restrict__ st1,
                    const float* __restrict__ W2, const float* __restrict__ b2,
                    unsigned short* __restrict__ geomU, float* __restrict__ partS) {
    __shared__ unsigned short ACTs[64*72];
    __shared__ float redS[16][16], redQ[16][16];
    const int tid = threadIdx.x;
    const int r = tid & 15, h4 = (tid>>4)&3, w = tid>>6;
    const int cp = tid & 31, rr = tid >> 5;
    bf16x8 wf[8];
    load_wfrags(W2, r, h4, wf);
    const float w1a0 = W1[2*cp],   w1a1 = W1[64+2*cp],   w1a2 = W1[128+2*cp];
    const float w1b0 = W1[2*cp+1], w1b1 = W1[64+2*cp+1], w1b2 = W1[128+2*cp+1];
    const float sca = st1[2*cp], scb = st1[2*cp+1];
    const float sfa = st1[64+2*cp], sfb = st1[64+2*cp+1];
    float accS[16], accQ[16];
    #pragma unroll
    for (int s = 0; s < 16; ++s) { accS[s] = 0.f; accQ[s] = 0.f; }
    #pragma unroll 1
    for (int m2 = blockIdx.x; m2 < Mq/2; m2 += GRID_SWEEP) {
        const int m0 = m2*2;
        const int P0 = m0*32;
        const float qa0=q_pts[m0*3+0],qa1=q_pts[m0*3+1],qa2=q_pts[m0*3+2];
        const float qb0=q_pts[m0*3+3],qb1=q_pts[m0*3+4],qb2=q_pts[m0*3+5];
        #pragma unroll
        for (int i = 0; i < 8; ++i) {
            int rrow = rr*8 + i;
            int idx = inds[P0 + rrow];
            float s0 = s_pts[idx*3+0], s1 = s_pts[idx*3+1], s2 = s_pts[idx*3+2];
            float d0, d1, d2;
            if (rrow < 32) { d0=s0-qa0; d1=s1-qa1; d2=s2-qa2; }
            else           { d0=s0-qb0; d1=s1-qb1; d2=s2-qb2; }
            float x1a = fmaf(d2,w1a2, fmaf(d1,w1a1, d0*w1a0));
            float x1b = fmaf(d2,w1b2, fmaf(d1,w1b1, d0*w1b0));
            float a0 = lrelu(fmaf(x1a, sca, sfa));
            float a1 = lrelu(fmaf(x1b, scb, sfb));
            unsigned int pk = (unsigned int)f2bf(a0) | ((unsigned int)f2bf(a1) << 16);
            *(unsigned int*)&ACTs[rrow*72 + 2*cp] = pk;
        }
        __syncthreads();
        bf16x8 af0 = *(const bf16x8*)&ACTs[(16*w + r)*72 + 8*h4];
        bf16x8 af1 = *(const bf16x8*)&ACTs[(16*w + r)*72 + 8*h4 + 32];
        __syncthreads();
        const int Prow = P0 + 16*w + r;
        const int idxr = inds[Prow];
        f32x4 acc[4];
        #pragma unroll
        for (int t = 0; t < 4; ++t) {
            float4 bb = *(const float4*)&b2[16*t + 4*h4];
            f32x4 c; c[0]=bb.x; c[1]=bb.y; c[2]=bb.z; c[3]=bb.w;
            c = __builtin_amdgcn_mfma_f32_16x16x32_bf16(wf[t*2+0], af0, c, 0, 0, 0);
            c = __builtin_amdgcn_mfma_f32_16x16x32_bf16(wf[t*2+1], af1, c, 0, 0, 0);
            acc[t] = c;
        }
        #pragma unroll
        for (int t = 0; t < 4; ++t) {
            unsigned short u0 = f2bf(acc[t][0]);
            unsigned short u1 = f2bf(acc[t][1]);
            unsigned short u2 = f2bf(acc[t][2]);
            unsigned short u3 = f2bf(acc[t][3]);
            ushort4 sv; sv.x=u0; sv.y=u1; sv.z=u2; sv.w=u3;
            *(ushort4*)&geomU[(size_t)Prow*64 + 16*t + 4*h4] = sv;
            float4 fv = *(const float4*)&s_feats[(size_t)idxr*64 + 16*t + 4*h4];
            float vp0 = fv.x - bf2f(u0); accS[t*4+0]+=vp0; accQ[t*4+0]=fmaf(vp0,vp0,accQ[t*4+0]);
            float vp1 = fv.y - bf2f(u1); accS[t*4+1]+=vp1; accQ[t*4+1]=fmaf(vp1,vp1,accQ[t*4+1]);
            float vp2 = fv.z - bf2f(u2); accS[t*4+2]+=vp2; accQ[t*4+2]=fmaf(vp2,vp2,accQ[t*4+2]);
            float vp3 = fv.w - bf2f(u3); accS[t*4+3]+=vp3; accQ[t*4+3]=fmaf(vp3,vp3,accQ[t*4+3]);
        }
    }
    #pragma unroll
    for (int s = 0; s < 16; ++s) {
        #pragma unroll
        for (int msk = 1; msk <= 8; msk <<= 1) {
            accS[s] += __shfl_xor(accS[s], msk);
            accQ[s] += __shfl_xor(accQ[s], msk);
        }
    }
    if (r == 0) {
        #pragma unroll
        for (int s = 0; s < 16; ++s) { redS[w*4+h4][s] = accS[s]; redQ[w*4+h4][s] = accQ[s]; }
    }
    __syncthreads();
    if (tid < 64) {
        int t = tid >> 4, hh = (tid >> 2) & 3, reg = tid & 3, s = t*4 + reg;
        float aS = 0.f, aQ = 0.f;
        #pragma unroll
        for (int ww = 0; ww < 4; ++ww) { aS += redS[ww*4+hh][s]; aQ += redQ[ww*4+hh][s]; }
        partS[blockIdx.x*128 + tid] = aS;
        partS[blockIdx.x*128 + 64 + tid] = aQ;
    }
}

// ---------------- K3e: v20 = v2[:,0,:] ; stats of q = v20 - geom (all h) ----------------
__launch_bounds__(256)
__global__ void k3e(const float* __restrict__ s_feats, const int* __restrict__ inds,
                    const bf16* __restrict__ geom, const float* __restrict__ st2,
                    const float* __restrict__ W, const float* __restrict__ bW,
                    float* __restrict__ v20, float* __restrict__ partS) {
    __shared__ float Bs[4*64];
    __shared__ float redS[256], redQ[256];
    const int tid = threadIdx.x, c = tid & 63, g = tid >> 6;
    float wcol[64];
    #pragma unroll
    for (int k = 0; k < 64; ++k) wcol[k] = W[k*64 + c];
    const float sc = st2[c], sf = st2[64+c], bias = bW[c];
    float accS = 0.f, accQ = 0.f;
    #pragma unroll 1
    for (int mb = blockIdx.x; mb < Mq/4; mb += GRID_SWEEP) {
        int m = mb*4 + g;
        size_t p0 = (size_t)m*32;
        int idx = inds[p0];
        float gm0 = __bfloat162float(geom[p0*64 + c]);
        float vp = s_feats[(size_t)idx*64 + c] - gm0;
        Bs[g*64 + c] = lrelu(fmaf(vp, sc, sf));
        __syncthreads();
        float v2v = dot64(&Bs[g*64], wcol, bias);
        v20[(size_t)m*64 + c] = v2v;
        #pragma unroll 4
        for (int h = 0; h < 32; ++h) {
            float gm = __bfloat162float(geom[(p0 + h)*64 + c]);
            float qv = v2v - gm;
            accS += qv; accQ = fmaf(qv, qv, accQ);
        }
        __syncthreads();
    }
    redS[tid] = accS; redQ[tid] = accQ;
    __syncthreads();
    if (tid < 64) {
        partS[blockIdx.x*128 + tid]      = redS[tid]+redS[64+tid]+redS[128+tid]+redS[192+tid];
        partS[blockIdx.x*128 + 64 + tid] = redQ[tid]+redQ[64+tid]+redQ[128+tid]+redQ[192+tid];
    }
}

// ---------------- K4 (MFMA): stats of x2 = lrelu(bn3(v20-geom))@aW1 ----------------
__launch_bounds__(256)
__global__ void k4m(const unsigned short* __restrict__ geomU, const float* __restrict__ v20,
                    const float* __restrict__ st3, const float* __restrict__ W,
                    float* __restrict__ partS) {
    __shared__ unsigned short ACTs[64*72];
    __shared__ float redS[16][16], redQ[16][16];
    const int tid = threadIdx.x;
    const int r = tid & 15, h4 = (tid>>4)&3, w = tid>>6;
    const int cp = tid & 31, rr = tid >> 5;
    bf16x8 wf[8];
    load_wfrags(W, r, h4, wf);
    const float sca = st3[2*cp], scb = st3[2*cp+1];
    const float sfa = st3[64+2*cp], sfb = st3[64+2*cp+1];
    float accS[16], accQ[16];
    #pragma unroll
    for (int s = 0; s < 16; ++s) { accS[s] = 0.f; accQ[s] = 0.f; }
    #pragma unroll 1
    for (int m2 = blockIdx.x; m2 < Mq/2; m2 += GRID_SWEEP) {
        const int m0 = m2*2;
        const int P0 = m0*32;
        float2 vA = *(const float2*)&v20[(size_t)m0*64 + 2*cp];
        float2 vB = *(const float2*)&v20[(size_t)(m0+1)*64 + 2*cp];
        #pragma unroll
        for (int i = 0; i < 8; ++i) {
            int rrow = rr*8 + i;
            unsigned int gv = *(const unsigned int*)&geomU[(size_t)(P0+rrow)*64 + 2*cp];
            float g0 = bf2f((unsigned short)(gv & 0xffff));
            float g1 = bf2f((unsigned short)(gv >> 16));
            float v0 = (rrow < 32) ? vA.x : vB.x;
            float v1 = (rrow < 32) ? vA.y : vB.y;
            float a0 = lrelu(fmaf(v0 - g0, sca, sfa));
            float a1 = lrelu(fmaf(v1 - g1, scb, sfb));
            unsigned int pk = (unsigned int)f2bf(a0) | ((unsigned int)f2bf(a1) << 16);
            *(unsigned int*)&ACTs[rrow*72 + 2*cp] = pk;
        }
        __syncthreads();
        bf16x8 af0 = *(const bf16x8*)&ACTs[(16*w + r)*72 + 8*h4];
        bf16x8 af1 = *(const bf16x8*)&ACTs[(16*w + r)*72 + 8*h4 + 32];
        __syncthreads();
        f32x4 acc[4];
        #pragma unroll
        for (int t = 0; t < 4; ++t) {
            f32x4 c = {0.f, 0.f, 0.f, 0.f};
            c = __builtin_amdgcn_mfma_f32_16x16x32_bf16(wf[t*2+0], af0, c, 0, 0, 0);
            c = __builtin_amdgcn_mfma_f32_16x16x32_bf16(wf[t*2+1], af1, c, 0, 0, 0);
            acc[t] = c;
        }
        #pragma unroll
        for (int t = 0; t < 4; ++t) {
            #pragma unroll
            for (int reg = 0; reg < 4; ++reg) {
                float x = acc[t][reg];
                accS[t*4+reg] += x;
                accQ[t*4+reg] = fmaf(x, x, accQ[t*4+reg]);
            }
        }
    }
    #pragma unroll
    for (int s = 0; s < 16; ++s) {
        #pragma unroll
        for (int msk = 1; msk <= 8; msk <<= 1) {
            accS[s] += __shfl_xor(accS[s], msk);
            accQ[s] += __shfl_xor(accQ[s], msk);
        }
    }
    if (r == 0) {
        #pragma unroll
        for (int s = 0; s < 16; ++s) { redS[w*4+h4][s] = accS[s]; redQ[w*4+h4][s] = accQ[s]; }
    }
    __syncthreads();
    if (tid < 64) {
        int t = tid >> 4, hh = (tid >> 2) & 3, reg = tid & 3, s = t*4 + reg;
        float aS = 0.f, aQ = 0.f;
        #pragma unroll
        for (int ww = 0; ww < 4; ++ww) { aS += redS[ww*4+hh][s]; aQ += redQ[ww*4+hh][s]; }
        partS[blockIdx.x*128 + tid] = aS;
        partS[blockIdx.x*128 + 64 + tid] = aQ;
    }
}

// ---------------- K5 (MFMA): x2 -> bn4 -> a3 -> softmax -> wnsG ----------------
__launch_bounds__(256)
__global__ void k5wm(const unsigned short* __restrict__ geomU, const float* __restrict__ v20,
                     const float* __restrict__ st3, const float* __restrict__ aW1,
                     const float* __restrict__ st4, const float* __restrict__ W2a,
                     const float* __restrict__ b2a, __half* __restrict__ wnsG) {
    __shared__ unsigned short ACTs[64*72];
    __shared__ float Ws[512];
    __shared__ float st4s[128];
    __shared__ float b2s[8];
    __shared__ float a3s[2*32*8];
    __shared__ float wns_s[2*256];
    const int tid = threadIdx.x;
    const int r = tid & 15, h4 = (tid>>4)&3, w = tid>>6;
    const int cp = tid & 31, rr = tid >> 5;
    bf16x8 wf[8];
    load_wfrags(aW1, r, h4, wf);
    Ws[tid] = W2a[tid];
    Ws[256 + tid] = W2a[256 + tid];
    if (tid < 128) st4s[tid] = st4[tid];
    if (tid < 8) b2s[tid] = b2a[tid];
    const float sca = st3[2*cp], scb = st3[2*cp+1];
    const float sfa = st3[64+2*cp], sfb = st3[64+2*cp+1];
    __syncthreads();
    #pragma unroll 1
    for (int m2 = blockIdx.x; m2 < Mq/2; m2 += GRID_SWEEP) {
        const int m0 = m2*2;
        const int P0 = m0*32;
        float2 vA = *(const float2*)&v20[(size_t)m0*64 + 2*cp];
        float2 vB = *(const float2*)&v20[(size_t)(m0+1)*64 + 2*cp];
        #pragma unroll
        for (int i = 0; i < 8; ++i) {
            int rrow = rr*8 + i;
            unsigned int gv = *(const unsigned int*)&geomU[(size_t)(P0+rrow)*64 + 2*cp];
            float g0 = bf2f((unsigned short)(gv & 0xffff));
            float g1 = bf2f((unsigned short)(gv >> 16));
            float v0 = (rrow < 32) ? vA.x : vB.x;
            float v1 = (rrow < 32) ? vA.y : vB.y;
            float a0 = lrelu(fmaf(v0 - g0, sca, sfa));
            float a1 = lrelu(fmaf(v1 - g1, scb, sfb));
            unsigned int pk = (unsigned int)f2bf(a0) | ((unsigned int)f2bf(a1) << 16);
            *(unsigned int*)&ACTs[rrow*72 + 2*cp] = pk;
        }
        __syncthreads();
        bf16x8 af0 = *(const bf16x8*)&ACTs[(16*w + r)*72 + 8*h4];
        bf16x8 af1 = *(const bf16x8*)&ACTs[(16*w + r)*72 + 8*h4 + 32];
        __syncthreads();
        f32x4 acc[4];
        #pragma unroll
        for (int t = 0; t < 4; ++t) {
            f32x4 c = {0.f, 0.f, 0.f, 0.f};
            c = __builtin_amdgcn_mfma_f32_16x16x32_bf16(wf[t*2+0], af0, c, 0, 0, 0);
            c = __builtin_amdgcn_mfma_f32_16x16x32_bf16(wf[t*2+1], af1, c, 0, 0, 0);
            acc[t] = c;
        }
        // bn4 + a3 partials over this lane's 16 channels
        float pa3[8];
        #pragma unroll
        for (int j = 0; j < 8; ++j) pa3[j] = 0.f;
        #pragma unroll
        for (int t = 0; t < 4; ++t) {
            #pragma unroll
            for (int reg = 0; reg < 4; ++reg) {
                int ch = 16*t + 4*h4 + reg;
                float a2 = lrelu(fmaf(acc[t][reg], st4s[ch], st4s[64+ch]));
                float4 w0 = *(const float4*)&Ws[ch*8];
                float4 w1 = *(const float4*)&Ws[ch*8 + 4];
                pa3[0] = fmaf(a2, w0.x, pa3[0]);
                pa3[1] = fmaf(a2, w0.y, pa3[1]);
                pa3[2] = fmaf(a2, w0.z, pa3[2]);
                pa3[3] = fmaf(a2, w0.w, pa3[3]);
                pa3[4] = fmaf(a2, w1.x, pa3[4]);
                pa3[5] = fmaf(a2, w1.y, pa3[5]);
                pa3[6] = fmaf(a2, w1.z, pa3[6]);
                pa3[7] = fmaf(a2, w1.w, pa3[7]);
            }
        }
        #pragma unroll
        for (int j = 0; j < 8; ++j) {
            pa3[j] += __shfl_xor(pa3[j], 16);
            pa3[j] += __shfl_xor(pa3[j], 32);
        }
        if ((tid & 63) < 16) {
            int pt = w >> 1, hrow = (w & 1)*16 + r;
            #pragma unroll
            for (int j = 0; j < 8; ++j) a3s[pt*256 + hrow*8 + j] = pa3[j] + b2s[j];
        }
        __syncthreads();
        if (tid < 16) {
            int pt = tid >> 3, j = tid & 7;
            float mx = -1e30f;
            for (int h = 0; h < 32; ++h) mx = fmaxf(mx, a3s[pt*256 + h*8 + j]);
            float sum = 0.f;
            for (int h = 0; h < 32; ++h) {
                float e = expf(a3s[pt*256 + h*8 + j] - mx);
                wns_s[pt*256 + h*8 + j] = e; sum += e;
            }
            float rcp = 1.f / sum;
            for (int h = 0; h < 32; ++h) wns_s[pt*256 + h*8 + j] *= rcp;
        }
        __syncthreads();
        {
            int u = tid*2, pt = u >> 8, off = u & 255;
            __half2 hv;
            hv.x = __float2half(wns_s[pt*256 + off]);
            hv.y = __float2half(wns_s[pt*256 + off + 1]);
            *(__half2*)&wnsG[(size_t)(m0 + pt)*256 + off] = hv;
        }
    }
}

// ---------------- K6 (MFMA): v2 = lrelu(bn2(feats-geom))@gW+gb ; out = sum_h v2*wns ----------------
__launch_bounds__(256)
__global__ void k6m(const float* __restrict__ s_feats, const int* __restrict__ inds,
                    const unsigned short* __restrict__ geomU, const float* __restrict__ st2,
                    const float* __restrict__ gW, const float* __restrict__ gb,
                    const __half* __restrict__ wnsG, float* __restrict__ out) {
    __shared__ unsigned short ACTs[64*72];
    __shared__ float wns2[2][256];    // transposed layout: [pt][j*32 + h]
    __shared__ float redO[16][16];
    const int tid = threadIdx.x;
    const int r = tid & 15, h4 = (tid>>4)&3, w = tid>>6;
    const int cp = tid & 31, rr = tid >> 5;
    bf16x8 wf[8];
    load_wfrags(gW, r, h4, wf);
    const float sca = st2[2*cp], scb = st2[2*cp+1];
    const float sfa = st2[64+2*cp], sfb = st2[64+2*cp+1];
    const int hRow = 16*(w & 1) + r;   // h of this thread's row within its point
    const int ptW  = w >> 1;           // which of the 2 points this wave's rows belong to
    #pragma unroll 1
    for (int m2 = blockIdx.x; m2 < Mq/2; m2 += GRID_SWEEP) {
        const int m0 = m2*2;
        const int P0 = m0*32;
        // Phase A: build bn2 activation rows (gathered s_feats - geom), bf16-packed into LDS
        #pragma unroll
        for (int i = 0; i < 8; ++i) {
            int rrow = rr*8 + i;
            int idx = inds[P0 + rrow];
            unsigned int gv = *(const unsigned int*)&geomU[(size_t)(P0+rrow)*64 + 2*cp];
            float2 fv = *(const float2*)&s_feats[(size_t)idx*64 + 2*cp];
            float g0 = bf2f((unsigned short)(gv & 0xffff));
            float g1 = bf2f((unsigned short)(gv >> 16));
            float a0 = lrelu(fmaf(fv.x - g0, sca, sfa));
            float a1 = lrelu(fmaf(fv.y - g1, scb, sfb));
            unsigned int pk = (unsigned int)f2bf(a0) | ((unsigned int)f2bf(a1) << 16);
            *(unsigned int*)&ACTs[rrow*72 + 2*cp] = pk;
        }
        // stage softmax weights for both points, transposed ([j*32+h]) for conflict-free reads
        {
            int u = tid*2;
            __half2 hv = *(const __half2*)&wnsG[(size_t)m0*256 + u];
            int pt0 = u >> 8, off0 = u & 255;
            wns2[pt0][(off0 & 7)*32 + (off0 >> 3)] = __half2float(hv.x);
            int off1 = off0 + 1;
            wns2[pt0][(off1 & 7)*32 + (off1 >> 3)] = __half2float(hv.y);
        }
        __syncthreads();
        bf16x8 af0 = *(const bf16x8*)&ACTs[(16*w + r)*72 + 8*h4];
        bf16x8 af1 = *(const bf16x8*)&ACTs[(16*w + r)*72 + 8*h4 + 32];
        __syncthreads();
        // Phase B: v2 row via MFMA (bias as C-in)
        f32x4 acc[4];
        #pragma unroll
        for (int t = 0; t < 4; ++t) {
            float4 bb = *(const float4*)&gb[16*t + 4*h4];
            f32x4 c; c[0]=bb.x; c[1]=bb.y; c[2]=bb.z; c[3]=bb.w;
            c = __builtin_amdgcn_mfma_f32_16x16x32_bf16(wf[t*2+0], af0, c, 0, 0, 0);
            c = __builtin_amdgcn_mfma_f32_16x16x32_bf16(wf[t*2+1], af1, c, 0, 0, 0);
            acc[t] = c;
        }
        // Phase C: weight by wns (j = 2t + (h4>>1), same for all reg) and reduce over 16 r-lanes
        float osum[16];
        #pragma unroll
        for (int t = 0; t < 4; ++t) {
            float wv = wns2[ptW][(2*t + (h4 >> 1))*32 + hRow];
            #pragma unroll
            for (int reg = 0; reg < 4; ++reg) osum[t*4+reg] = acc[t][reg] * wv;
        }
        #pragma unroll
        for (int s = 0; s < 16; ++s) {
            #pragma unroll
            for (int msk = 1; msk <= 8; msk <<= 1)
                osum[s] += __shfl_xor(osum[s], msk);
        }
        if (r == 0) {
            #pragma unroll
            for (int s = 0; s < 16; ++s) redO[w*4+h4][s] = osum[s];
        }
        __syncthreads();
        // Phase D: combine the two waves of each point, write out
        if (tid < 128) {
            int pt = tid >> 6, i2 = tid & 63;
            int t = i2 >> 4, hh = (i2 >> 2) & 3, reg = i2 & 3, s = t*4 + reg;
            float val = redO[(pt*2)*4 + hh][s] + redO[(pt*2+1)*4 + hh][s];
            out[(size_t)(m0 + pt)*64 + 16*t + 4*hh + reg] = val;
        }
        __syncthreads();
    }
}

extern "C" void kernel_launch(void* const* d_in, const int* in_sizes, int n_in,
                              void* d_out, int out_size, void* d_ws, size_t ws_size,
                              hipStream_t stream) {
    const float* q_pts   = (const float*)d_in[0];
    const float* s_pts   = (const float*)d_in[1];
    const float* s_feats = (const float*)d_in[2];
    const int*   inds    = (const int*)d_in[3];
    const float* dW1 = (const float*)d_in[4];
    const float* dbg = (const float*)d_in[5];
    const float* dbb = (const float*)d_in[6];
    const float* dW2 = (const float*)d_in[7];
    const float* db2 = (const float*)d_in[8];
    const float* gng = (const float*)d_in[9];
    const float* gnb = (const float*)d_in[10];
    const float* gW  = (const float*)d_in[11];
    const float* gb  = (const float*)d_in[12];
    const float* ang = (const float*)d_in[13];
    const float* anb = (const float*)d_in[14];
    const float* aW1 = (const float*)d_in[15];
    const float* abg = (const float*)d_in[16];
    const float* abb = (const float*)d_in[17];
    const float* aW2 = (const float*)d_in[18];
    const float* ab2 = (const float*)d_in[19];
    float* out = (float*)d_out;

    char* ws = (char*)d_ws;
    float* part1 = (float*)ws;                           // 64KB
    float* partS = (float*)(ws + (1<<20));               // 1MB
    float* st1   = (float*)(ws + (2<<20));
    float* st2 = st1 + 128;
    float* st3 = st1 + 256;
    float* st4 = st1 + 384;
    float* v20  = (float*)(ws + (3<<20));                // 12.8MB
    const size_t szG = (size_t)MHt * 64 * 2;             // 204.8MB bf16

    bf16*  geom = (bf16*)(ws + ((size_t)16<<20));
    unsigned short* geomU = (unsigned short*)geom;
    __half* wnsG = (__half*)(ws + ((size_t)16<<20) + szG);
    const size_t needE2 = ((size_t)16<<20) + szG + (size_t)Mq*256*2;  // ~246.4MB (validated present)

    if (ws_size < needE2) return;

    k1_moments<<<GRID_K1, 256, 0, stream>>>(q_pts, s_pts, inds, part1);
    kfin1<<<1, 1024, 0, stream>>>(part1, dW1, dbg, dbb, st1);
    k2m<<<GRID_SWEEP, 256, 0, stream>>>(q_pts, s_pts, s_feats, inds, dW1, st1, dW2, db2, geomU, partS);
    kfinS<<<1, 1024, 0, stream>>>(partS, gng, gnb, st2);
    k3e<<<GRID_SWEEP, 256, 0, stream>>>(s_feats, inds, geom, st2, gW, gb, v20, partS);
    kfinS<<<1, 1024, 0, stream>>>(partS, ang, anb, st3);
    k4m<<<GRID_SWEEP, 256, 0, stream>>>(geomU, v20, st3, aW1, partS);
    kfinS<<<1, 1024, 0, stream>>>(partS, abg, abb, st4);
    k5wm<<<GRID_SWEEP, 256, 0, stream>>>(geomU, v20, st3, aW1, st4, aW2, ab2, wnsG);
    k6m<<<GRID_SWEEP, 256, 0, stream>>>(s_feats, inds, geomU, st2, gW, gb, wnsG, out);
}

// Round 12
// 772.359 us; speedup vs baseline: 4.4155x; 1.0879x over previous
//
#include <hip/hip_runtime.h>
#include <hip/hip_bf16.h>
#include <hip/hip_fp16.h>
#include <math.h>

#define Mq 50000
#define Hh 32
#define MHt 1600000
#define SLOPE 0.1f

#define GRID_K1 1024
#define GRID_SWEEP 2048

typedef __hip_bfloat16 bf16;
using bf16x8 = __attribute__((ext_vector_type(8))) short;
using f32x4  = __attribute__((ext_vector_type(4))) float;

__device__ __forceinline__ float lrelu(float x) { return x >= 0.f ? x : SLOPE * x; }

__device__ __forceinline__ unsigned short f2bf(float x) {
    union { __hip_bfloat16 b; unsigned short u; } cv;
    cv.b = __float2bfloat16(x);
    return cv.u;
}
__device__ __forceinline__ float bf2f(unsigned short u) {
    union { float f; unsigned int i; } cv;
    cv.i = ((unsigned int)u) << 16;
    return cv.f;
}

// 64-wide fp32 dot (k3e only)
__device__ __forceinline__ float dot64(const float* row, const float* wc, float acc) {
    #pragma unroll
    for (int k4 = 0; k4 < 16; ++k4) {
        float4 a4 = *reinterpret_cast<const float4*>(&row[k4*4]);
        acc = fmaf(a4.x, wc[4*k4+0], acc);
        acc = fmaf(a4.y, wc[4*k4+1], acc);
        acc = fmaf(a4.z, wc[4*k4+2], acc);
        acc = fmaf(a4.w, wc[4*k4+3], acc);
    }
    return acc;
}

// Load W^T A-fragments for D = W^T @ ACT^T scheme.
// wf[t*2+kc] elem j = bf16( W[8*h4 + j + 32*kc][16*t + r] ),  W row-major [64k][64n]
__device__ __forceinline__ void load_wfrags(const float* __restrict__ W, int r, int h4, bf16x8* wf) {
    #pragma unroll
    for (int t = 0; t < 4; ++t) {
        #pragma unroll
        for (int kc = 0; kc < 2; ++kc) {
            bf16x8 v;
            #pragma unroll
            for (int j = 0; j < 8; ++j)
                v[j] = (short)f2bf(W[(8*h4 + j + 32*kc)*64 + 16*t + r]);
            wf[t*2 + kc] = v;
        }
    }
}

// ---------------- K1: moments of nbrs (analytic bn1 stats) ----------------
__launch_bounds__(256)
__global__ void k1_moments(const float* __restrict__ q_pts, const float* __restrict__ s_pts,
                           const int* __restrict__ inds, float* __restrict__ part1) {
    float a0=0.f,a1=0.f,a2=0.f,q00=0.f,q01=0.f,q02=0.f,q11=0.f,q12=0.f,q22=0.f;
    int tid = blockIdx.x * 256 + threadIdx.x;
    for (int p = tid; p < MHt; p += GRID_K1 * 256) {
        int m = p >> 5;
        int idx = inds[p];
        float d0 = s_pts[idx*3+0] - q_pts[m*3+0];
        float d1 = s_pts[idx*3+1] - q_pts[m*3+1];
        float d2 = s_pts[idx*3+2] - q_pts[m*3+2];
        a0 += d0; a1 += d1; a2 += d2;
        q00 = fmaf(d0,d0,q00); q01 = fmaf(d0,d1,q01); q02 = fmaf(d0,d2,q02);
        q11 = fmaf(d1,d1,q11); q12 = fmaf(d1,d2,q12); q22 = fmaf(d2,d2,q22);
    }
    #pragma unroll
    for (int off = 32; off > 0; off >>= 1) {
        a0 += __shfl_down(a0,off); a1 += __shfl_down(a1,off); a2 += __shfl_down(a2,off);
        q00 += __shfl_down(q00,off); q01 += __shfl_down(q01,off); q02 += __shfl_down(q02,off);
        q11 += __shfl_down(q11,off); q12 += __shfl_down(q12,off); q22 += __shfl_down(q22,off);
    }
    __shared__ float sh[4][12];
    int lane = threadIdx.x & 63, wv = threadIdx.x >> 6;
    if (lane == 0) {
        float* r = sh[wv];
        r[0]=a0; r[1]=a1; r[2]=a2; r[3]=q00; r[4]=q01; r[5]=q02; r[6]=q11; r[7]=q12; r[8]=q22;
    }
    __syncthreads();
    if (threadIdx.x < 9) {
        float s = sh[0][threadIdx.x] + sh[1][threadIdx.x] + sh[2][threadIdx.x] + sh[3][threadIdx.x];
        part1[blockIdx.x * 16 + threadIdx.x] = s;
    }
}

// ---------------- fin1 ----------------
__global__ void kfin1(const float* __restrict__ part1, const float* __restrict__ W1,
                      const float* __restrict__ gam, const float* __restrict__ bet,
                      float* __restrict__ st) {
    __shared__ float shf[64][16];
    __shared__ double shd[9];
    int t = threadIdx.x;
    int col = t & 15, sl = t >> 4;
    float acc = 0.f;
    for (int r = sl; r < GRID_K1; r += 64) acc += part1[r*16 + col];
    shf[sl][col] = acc;
    __syncthreads();
    if (t < 9) {
        double s = 0.0;
        for (int i = 0; i < 64; ++i) s += (double)shf[i][t];
        shd[t] = s;
    }
    __syncthreads();
    if (t < 64) {
        double S0=shd[0],S1=shd[1],S2=shd[2],P00=shd[3],P01=shd[4],P02=shd[5],P11=shd[6],P12=shd[7],P22=shd[8];
        double w0 = W1[t], w1 = W1[64+t], w2 = W1[128+t];
        double inv = 1.0 / (double)MHt;
        double mean = (S0*w0 + S1*w1 + S2*w2) * inv;
        double e2 = (P00*w0*w0 + P11*w1*w1 + P22*w2*w2 + 2.0*(P01*w0*w1 + P02*w0*w2 + P12*w1*w2)) * inv;
        double var = e2 - mean*mean;
        double scale = (double)gam[t] / sqrt(var + 1e-5);
        st[t] = (float)scale;
        st[64+t] = (float)((double)bet[t] - mean*scale);
    }
}

// ---------------- finS ----------------
__global__ void kfinS(const float* __restrict__ partS, const float* __restrict__ gam,
                      const float* __restrict__ bet, float* __restrict__ st) {
    __shared__ float shf[8][128];
    __shared__ double shd[128];
    int t = threadIdx.x;
    int col = t & 127, sl = t >> 7;
    float acc = 0.f;
    for (int r = sl; r < GRID_SWEEP; r += 8) acc += partS[r*128 + col];
    shf[sl][col] = acc;
    __syncthreads();
    if (t < 128) {
        double s = 0.0;
        #pragma unroll
        for (int i = 0; i < 8; ++i) s += (double)shf[i][t];
        shd[t] = s;
    }
    __syncthreads();
    if (t < 64) {
        double inv = 1.0 / (double)MHt;
        double mean = shd[t] * inv;
        double var = shd[64+t] * inv - mean*mean;
        double scale = (double)gam[t] / sqrt(var + 1e-5);
        st[t] = (float)scale;
        st[64+t] = (float)((double)bet[t] - mean*scale);
    }
}

// ---------------- K2 (MFMA): geom = lrelu(bn1(nbrs@W1))@W2+b2 ; stats of v'=feats-geom ----------------
__launch_bounds__(256)
__global__ void k2m(const float* __restrict__ q_pts, const float* __restrict__ s_pts,
                    const float* __restrict__ s_feats, const int* __restrict__ inds,
                    const float* __restrict__ W1, const float* __restrict__ st1,
                    const float* __restrict__ W2, const float* __restrict__ b2,
                    unsigned short* __restrict__ geomU, float* __restrict__ partS) {
    __shared__ unsigned short ACTs[64*72];
    __shared__ float redS[16][16], redQ[16][16];
    const int tid = threadIdx.x;
    const int r = tid & 15, h4 = (tid>>4)&3, w = tid>>6;
    const int cp = tid & 31, rr = tid >> 5;
    bf16x8 wf[8];
    load_wfrags(W2, r, h4, wf);
    const float w1a0 = W1[2*cp],   w1a1 = W1[64+2*cp],   w1a2 = W1[128+2*cp];
    const float w1b0 = W1[2*cp+1], w1b1 = W1[64+2*cp+1], w1b2 = W1[128+2*cp+1];
    const float sca = st1[2*cp], scb = st1[2*cp+1];
    const float sfa = st1[64+2*cp], sfb = st1[64+2*cp+1];
    float accS[16], accQ[16];
    #pragma unroll
    for (int s = 0; s < 16; ++s) { accS[s] = 0.f; accQ[s] = 0.f; }
    #pragma unroll 1
    for (int m2 = blockIdx.x; m2 < Mq/2; m2 += GRID_SWEEP) {
        const int m0 = m2*2;
        const int P0 = m0*32;
        const float qa0=q_pts[m0*3+0],qa1=q_pts[m0*3+1],qa2=q_pts[m0*3+2];
        const float qb0=q_pts[m0*3+3],qb1=q_pts[m0*3+4],qb2=q_pts[m0*3+5];
        #pragma unroll
        for (int i = 0; i < 8; ++i) {
            int rrow = rr*8 + i;
            int idx = inds[P0 + rrow];
            float s0 = s_pts[idx*3+0], s1 = s_pts[idx*3+1], s2 = s_pts[idx*3+2];
            float d0, d1, d2;
            if (rrow < 32) { d0=s0-qa0; d1=s1-qa1; d2=s2-qa2; }
            else           { d0=s0-qb0; d1=s1-qb1; d2=s2-qb2; }
            float x1a = fmaf(d2,w1a2, fmaf(d1,w1a1, d0*w1a0));
            float x1b = fmaf(d2,w1b2, fmaf(d1,w1b1, d0*w1b0));
            float a0 = lrelu(fmaf(x1a, sca, sfa));
            float a1 = lrelu(fmaf(x1b, scb, sfb));
            unsigned int pk = (unsigned int)f2bf(a0) | ((unsigned int)f2bf(a1) << 16);
            *(unsigned int*)&ACTs[rrow*72 + 2*cp] = pk;
        }
        __syncthreads();
        bf16x8 af0 = *(const bf16x8*)&ACTs[(16*w + r)*72 + 8*h4];
        bf16x8 af1 = *(const bf16x8*)&ACTs[(16*w + r)*72 + 8*h4 + 32];
        __syncthreads();
        const int Prow = P0 + 16*w + r;
        const int idxr = inds[Prow];
        f32x4 acc[4];
        #pragma unroll
        for (int t = 0; t < 4; ++t) {
            float4 bb = *(const float4*)&b2[16*t + 4*h4];
            f32x4 c; c[0]=bb.x; c[1]=bb.y; c[2]=bb.z; c[3]=bb.w;
            c = __builtin_amdgcn_mfma_f32_16x16x32_bf16(wf[t*2+0], af0, c, 0, 0, 0);
            c = __builtin_amdgcn_mfma_f32_16x16x32_bf16(wf[t*2+1], af1, c, 0, 0, 0);
            acc[t] = c;
        }
        #pragma unroll
        for (int t = 0; t < 4; ++t) {
            unsigned short u0 = f2bf(acc[t][0]);
            unsigned short u1 = f2bf(acc[t][1]);
            unsigned short u2 = f2bf(acc[t][2]);
            unsigned short u3 = f2bf(acc[t][3]);
            ushort4 sv; sv.x=u0; sv.y=u1; sv.z=u2; sv.w=u3;
            *(ushort4*)&geomU[(size_t)Prow*64 + 16*t + 4*h4] = sv;
            float4 fv = *(const float4*)&s_feats[(size_t)idxr*64 + 16*t + 4*h4];
            float vp0 = fv.x - bf2f(u0); accS[t*4+0]+=vp0; accQ[t*4+0]=fmaf(vp0,vp0,accQ[t*4+0]);
            float vp1 = fv.y - bf2f(u1); accS[t*4+1]+=vp1; accQ[t*4+1]=fmaf(vp1,vp1,accQ[t*4+1]);
            float vp2 = fv.z - bf2f(u2); accS[t*4+2]+=vp2; accQ[t*4+2]=fmaf(vp2,vp2,accQ[t*4+2]);
            float vp3 = fv.w - bf2f(u3); accS[t*4+3]+=vp3; accQ[t*4+3]=fmaf(vp3,vp3,accQ[t*4+3]);
        }
    }
    #pragma unroll
    for (int s = 0; s < 16; ++s) {
        #pragma unroll
        for (int msk = 1; msk <= 8; msk <<= 1) {
            accS[s] += __shfl_xor(accS[s], msk);
            accQ[s] += __shfl_xor(accQ[s], msk);
        }
    }
    if (r == 0) {
        #pragma unroll
        for (int s = 0; s < 16; ++s) { redS[w*4+h4][s] = accS[s]; redQ[w*4+h4][s] = accQ[s]; }
    }
    __syncthreads();
    if (tid < 64) {
        int t = tid >> 4, hh = (tid >> 2) & 3, reg = tid & 3, s = t*4 + reg;
        float aS = 0.f, aQ = 0.f;
        #pragma unroll
        for (int ww = 0; ww < 4; ++ww) { aS += redS[ww*4+hh][s]; aQ += redQ[ww*4+hh][s]; }
        partS[blockIdx.x*128 + tid] = aS;
        partS[blockIdx.x*128 + 64 + tid] = aQ;
    }
}

// ---------------- K3e: v20 = v2[:,0,:] ; stats of q = v20 - geom (all h) ----------------
__launch_bounds__(256)
__global__ void k3e(const float* __restrict__ s_feats, const int* __restrict__ inds,
                    const bf16* __restrict__ geom, const float* __restrict__ st2,
                    const float* __restrict__ W, const float* __restrict__ bW,
                    float* __restrict__ v20, float* __restrict__ partS) {
    __shared__ float Bs[4*64];
    __shared__ float redS[256], redQ[256];
    const int tid = threadIdx.x, c = tid & 63, g = tid >> 6;
    float wcol[64];
    #pragma unroll
    for (int k = 0; k < 64; ++k) wcol[k] = W[k*64 + c];
    const float sc = st2[c], sf = st2[64+c], bias = bW[c];
    float accS = 0.f, accQ = 0.f;
    #pragma unroll 1
    for (int mb = blockIdx.x; mb < Mq/4; mb += GRID_SWEEP) {
        int m = mb*4 + g;
        size_t p0 = (size_t)m*32;
        int idx = inds[p0];
        float gm0 = __bfloat162float(geom[p0*64 + c]);
        float vp = s_feats[(size_t)idx*64 + c] - gm0;
        Bs[g*64 + c] = lrelu(fmaf(vp, sc, sf));
        __syncthreads();
        float v2v = dot64(&Bs[g*64], wcol, bias);
        v20[(size_t)m*64 + c] = v2v;
        #pragma unroll 4
        for (int h = 0; h < 32; ++h) {
            float gm = __bfloat162float(geom[(p0 + h)*64 + c]);
            float qv = v2v - gm;
            accS += qv; accQ = fmaf(qv, qv, accQ);
        }
        __syncthreads();
    }
    redS[tid] = accS; redQ[tid] = accQ;
    __syncthreads();
    if (tid < 64) {
        partS[blockIdx.x*128 + tid]      = redS[tid]+redS[64+tid]+redS[128+tid]+redS[192+tid];
        partS[blockIdx.x*128 + 64 + tid] = redQ[tid]+redQ[64+tid]+redQ[128+tid]+redQ[192+tid];
    }
}

// ---------------- K4 (MFMA): stats of x2 = lrelu(bn3(v20-geom))@aW1 ----------------
__launch_bounds__(256)
__global__ void k4m(const unsigned short* __restrict__ geomU, const float* __restrict__ v20,
                    const float* __restrict__ st3, const float* __restrict__ W,
                    float* __restrict__ partS) {
    __shared__ unsigned short ACTs[64*72];
    __shared__ float redS[16][16], redQ[16][16];
    const int tid = threadIdx.x;
    const int r = tid & 15, h4 = (tid>>4)&3, w = tid>>6;
    const int cp = tid & 31, rr = tid >> 5;
    bf16x8 wf[8];
    load_wfrags(W, r, h4, wf);
    const float sca = st3[2*cp], scb = st3[2*cp+1];
    const float sfa = st3[64+2*cp], sfb = st3[64+2*cp+1];
    float accS[16], accQ[16];
    #pragma unroll
    for (int s = 0; s < 16; ++s) { accS[s] = 0.f; accQ[s] = 0.f; }
    #pragma unroll 1
    for (int m2 = blockIdx.x; m2 < Mq/2; m2 += GRID_SWEEP) {
        const int m0 = m2*2;
        const int P0 = m0*32;
        float2 vA = *(const float2*)&v20[(size_t)m0*64 + 2*cp];
        float2 vB = *(const float2*)&v20[(size_t)(m0+1)*64 + 2*cp];
        #pragma unroll
        for (int i = 0; i < 8; ++i) {
            int rrow = rr*8 + i;
            unsigned int gv = *(const unsigned int*)&geomU[(size_t)(P0+rrow)*64 + 2*cp];
            float g0 = bf2f((unsigned short)(gv & 0xffff));
            float g1 = bf2f((unsigned short)(gv >> 16));
            float v0 = (rrow < 32) ? vA.x : vB.x;
            float v1 = (rrow < 32) ? vA.y : vB.y;
            float a0 = lrelu(fmaf(v0 - g0, sca, sfa));
            float a1 = lrelu(fmaf(v1 - g1, scb, sfb));
            unsigned int pk = (unsigned int)f2bf(a0) | ((unsigned int)f2bf(a1) << 16);
            *(unsigned int*)&ACTs[rrow*72 + 2*cp] = pk;
        }
        __syncthreads();
        bf16x8 af0 = *(const bf16x8*)&ACTs[(16*w + r)*72 + 8*h4];
        bf16x8 af1 = *(const bf16x8*)&ACTs[(16*w + r)*72 + 8*h4 + 32];
        __syncthreads();
        f32x4 acc[4];
        #pragma unroll
        for (int t = 0; t < 4; ++t) {
            f32x4 c = {0.f, 0.f, 0.f, 0.f};
            c = __builtin_amdgcn_mfma_f32_16x16x32_bf16(wf[t*2+0], af0, c, 0, 0, 0);
            c = __builtin_amdgcn_mfma_f32_16x16x32_bf16(wf[t*2+1], af1, c, 0, 0, 0);
            acc[t] = c;
        }
        #pragma unroll
        for (int t = 0; t < 4; ++t) {
            #pragma unroll
            for (int reg = 0; reg < 4; ++reg) {
                float x = acc[t][reg];
                accS[t*4+reg] += x;
                accQ[t*4+reg] = fmaf(x, x, accQ[t*4+reg]);
            }
        }
    }
    #pragma unroll
    for (int s = 0; s < 16; ++s) {
        #pragma unroll
        for (int msk = 1; msk <= 8; msk <<= 1) {
            accS[s] += __shfl_xor(accS[s], msk);
            accQ[s] += __shfl_xor(accQ[s], msk);
        }
    }
    if (r == 0) {
        #pragma unroll
        for (int s = 0; s < 16; ++s) { redS[w*4+h4][s] = accS[s]; redQ[w*4+h4][s] = accQ[s]; }
    }
    __syncthreads();
    if (tid < 64) {
        int t = tid >> 4, hh = (tid >> 2) & 3, reg = tid & 3, s = t*4 + reg;
        float aS = 0.f, aQ = 0.f;
        #pragma unroll
        for (int ww = 0; ww < 4; ++ww) { aS += redS[ww*4+hh][s]; aQ += redQ[ww*4+hh][s]; }
        partS[blockIdx.x*128 + tid] = aS;
        partS[blockIdx.x*128 + 64 + tid] = aQ;
    }
}

// ---------------- K5 (MFMA): x2 -> bn4 -> a3 -> parallel softmax -> wnsG ----------------
__launch_bounds__(256)
__global__ void k5wm(const unsigned short* __restrict__ geomU, const float* __restrict__ v20,
                     const float* __restrict__ st3, const float* __restrict__ aW1,
                     const float* __restrict__ st4, const float* __restrict__ W2a,
                     const float* __restrict__ b2a, __half* __restrict__ wnsG) {
    __shared__ unsigned short ACTs[64*72];
    __shared__ float Ws[512];
    __shared__ float st4s[128];
    __shared__ float b2s[8];
    __shared__ float a3s[2*288];      // padded rows (stride 9) -> conflict-free softmax reads
    __shared__ float wns_s[2*256];
    const int tid = threadIdx.x;
    const int r = tid & 15, h4 = (tid>>4)&3, w = tid>>6;
    const int cp = tid & 31, rr = tid >> 5;
    bf16x8 wf[8];
    load_wfrags(aW1, r, h4, wf);
    Ws[tid] = W2a[tid];
    Ws[256 + tid] = W2a[256 + tid];
    if (tid < 128) st4s[tid] = st4[tid];
    if (tid < 8) b2s[tid] = b2a[tid];
    const float sca = st3[2*cp], scb = st3[2*cp+1];
    const float sfa = st3[64+2*cp], sfb = st3[64+2*cp+1];
    // parallel-softmax thread mapping: 16 groups (pt,j) x 16 lanes, 2 h per lane
    const int spt = tid >> 7, sj = (tid >> 4) & 7, si = tid & 15;
    __syncthreads();
    #pragma unroll 1
    for (int m2 = blockIdx.x; m2 < Mq/2; m2 += GRID_SWEEP) {
        const int m0 = m2*2;
        const int P0 = m0*32;
        float2 vA = *(const float2*)&v20[(size_t)m0*64 + 2*cp];
        float2 vB = *(const float2*)&v20[(size_t)(m0+1)*64 + 2*cp];
        #pragma unroll
        for (int i = 0; i < 8; ++i) {
            int rrow = rr*8 + i;
            unsigned int gv = *(const unsigned int*)&geomU[(size_t)(P0+rrow)*64 + 2*cp];
            float g0 = bf2f((unsigned short)(gv & 0xffff));
            float g1 = bf2f((unsigned short)(gv >> 16));
            float v0 = (rrow < 32) ? vA.x : vB.x;
            float v1 = (rrow < 32) ? vA.y : vB.y;
            float a0 = lrelu(fmaf(v0 - g0, sca, sfa));
            float a1 = lrelu(fmaf(v1 - g1, scb, sfb));
            unsigned int pk = (unsigned int)f2bf(a0) | ((unsigned int)f2bf(a1) << 16);
            *(unsigned int*)&ACTs[rrow*72 + 2*cp] = pk;
        }
        __syncthreads();
        bf16x8 af0 = *(const bf16x8*)&ACTs[(16*w + r)*72 + 8*h4];
        bf16x8 af1 = *(const bf16x8*)&ACTs[(16*w + r)*72 + 8*h4 + 32];
        __syncthreads();
        f32x4 acc[4];
        #pragma unroll
        for (int t = 0; t < 4; ++t) {
            f32x4 c = {0.f, 0.f, 0.f, 0.f};
            c = __builtin_amdgcn_mfma_f32_16x16x32_bf16(wf[t*2+0], af0, c, 0, 0, 0);
            c = __builtin_amdgcn_mfma_f32_16x16x32_bf16(wf[t*2+1], af1, c, 0, 0, 0);
            acc[t] = c;
        }
        // bn4 + a3 partials over this lane's 16 channels
        float pa3[8];
        #pragma unroll
        for (int j = 0; j < 8; ++j) pa3[j] = 0.f;
        #pragma unroll
        for (int t = 0; t < 4; ++t) {
            #pragma unroll
            for (int reg = 0; reg < 4; ++reg) {
                int ch = 16*t + 4*h4 + reg;
                float a2 = lrelu(fmaf(acc[t][reg], st4s[ch], st4s[64+ch]));
                float4 w0 = *(const float4*)&Ws[ch*8];
                float4 w1 = *(const float4*)&Ws[ch*8 + 4];
                pa3[0] = fmaf(a2, w0.x, pa3[0]);
                pa3[1] = fmaf(a2, w0.y, pa3[1]);
                pa3[2] = fmaf(a2, w0.z, pa3[2]);
                pa3[3] = fmaf(a2, w0.w, pa3[3]);
                pa3[4] = fmaf(a2, w1.x, pa3[4]);
                pa3[5] = fmaf(a2, w1.y, pa3[5]);
                pa3[6] = fmaf(a2, w1.z, pa3[6]);
                pa3[7] = fmaf(a2, w1.w, pa3[7]);
            }
        }
        #pragma unroll
        for (int j = 0; j < 8; ++j) {
            pa3[j] += __shfl_xor(pa3[j], 16);
            pa3[j] += __shfl_xor(pa3[j], 32);
        }
        if ((tid & 63) < 16) {
            int pt = w >> 1, hrow = (w & 1)*16 + r;
            #pragma unroll
            for (int j = 0; j < 8; ++j) a3s[pt*288 + hrow*9 + j] = pa3[j] + b2s[j];
        }
        __syncthreads();
        // parallel softmax over h for each (pt,j): 16 lanes, 2 h each, shfl_xor reduce
        {
            float v0 = a3s[spt*288 + si*9 + sj];
            float v1 = a3s[spt*288 + (si+16)*9 + sj];
            float mx = fmaxf(v0, v1);
            #pragma unroll
            for (int msk = 1; msk <= 8; msk <<= 1) mx = fmaxf(mx, __shfl_xor(mx, msk));
            float e0 = expf(v0 - mx), e1 = expf(v1 - mx);
            float s = e0 + e1;
            #pragma unroll
            for (int msk = 1; msk <= 8; msk <<= 1) s += __shfl_xor(s, msk);
            float rcp = 1.f / s;
            wns_s[spt*256 + si*8 + sj] = e0 * rcp;
            wns_s[spt*256 + (si+16)*8 + sj] = e1 * rcp;
        }
        __syncthreads();
        {
            int u = tid*2, pt = u >> 8, off = u & 255;
            __half2 hv;
            hv.x = __float2half(wns_s[pt*256 + off]);
            hv.y = __float2half(wns_s[pt*256 + off + 1]);
            *(__half2*)&wnsG[(size_t)(m0 + pt)*256 + off] = hv;
        }
    }
}

// ---------------- K6 (MFMA): v2 = lrelu(bn2(feats-geom))@gW+gb ; out = sum_h v2*wns ----------------
__launch_bounds__(256)
__global__ void k6m(const float* __restrict__ s_feats, const int* __restrict__ inds,
                    const unsigned short* __restrict__ geomU, const float* __restrict__ st2,
                    const float* __restrict__ gW, const float* __restrict__ gb,
                    const __half* __restrict__ wnsG, float* __restrict__ out) {
    __shared__ unsigned short ACTs[64*72];
    __shared__ float wns2[2][256];    // transposed layout: [pt][j*32 + h]
    __shared__ float redO[16][16];
    const int tid = threadIdx.x;
    const int r = tid & 15, h4 = (tid>>4)&3, w = tid>>6;
    const int cp = tid & 31, rr = tid >> 5;
    bf16x8 wf[8];
    load_wfrags(gW, r, h4, wf);
    const float sca = st2[2*cp], scb = st2[2*cp+1];
    const float sfa = st2[64+2*cp], sfb = st2[64+2*cp+1];
    const int hRow = 16*(w & 1) + r;   // h of this thread's row within its point
    const int ptW  = w >> 1;           // which of the 2 points this wave's rows belong to
    #pragma unroll 1
    for (int m2 = blockIdx.x; m2 < Mq/2; m2 += GRID_SWEEP) {
        const int m0 = m2*2;
        const int P0 = m0*32;
        // Phase A: build bn2 activation rows (gathered s_feats - geom), bf16-packed into LDS
        #pragma unroll
        for (int i = 0; i < 8; ++i) {
            int rrow = rr*8 + i;
            int idx = inds[P0 + rrow];
            unsigned int gv = *(const unsigned int*)&geomU[(size_t)(P0+rrow)*64 + 2*cp];
            float2 fv = *(const float2*)&s_feats[(size_t)idx*64 + 2*cp];
            float g0 = bf2f((unsigned short)(gv & 0xffff));
            float g1 = bf2f((unsigned short)(gv >> 16));
            float a0 = lrelu(fmaf(fv.x - g0, sca, sfa));
            float a1 = lrelu(fmaf(fv.y - g1, scb, sfb));
            unsigned int pk = (unsigned int)f2bf(a0) | ((unsigned int)f2bf(a1) << 16);
            *(unsigned int*)&ACTs[rrow*72 + 2*cp] = pk;
        }
        // stage softmax weights for both points, transposed ([j*32+h]) for conflict-free reads
        {
            int u = tid*2;
            __half2 hv = *(const __half2*)&wnsG[(size_t)m0*256 + u];
            int pt0 = u >> 8, off0 = u & 255;
            wns2[pt0][(off0 & 7)*32 + (off0 >> 3)] = __half2float(hv.x);
            int off1 = off0 + 1;
            wns2[pt0][(off1 & 7)*32 + (off1 >> 3)] = __half2float(hv.y);
        }
        __syncthreads();
        bf16x8 af0 = *(const bf16x8*)&ACTs[(16*w + r)*72 + 8*h4];
        bf16x8 af1 = *(const bf16x8*)&ACTs[(16*w + r)*72 + 8*h4 + 32];
        __syncthreads();
        // Phase B: v2 row via MFMA (bias as C-in)
        f32x4 acc[4];
        #pragma unroll
        for (int t = 0; t < 4; ++t) {
            float4 bb = *(const float4*)&gb[16*t + 4*h4];
            f32x4 c; c[0]=bb.x; c[1]=bb.y; c[2]=bb.z; c[3]=bb.w;
            c = __builtin_amdgcn_mfma_f32_16x16x32_bf16(wf[t*2+0], af0, c, 0, 0, 0);
            c = __builtin_amdgcn_mfma_f32_16x16x32_bf16(wf[t*2+1], af1, c, 0, 0, 0);
            acc[t] = c;
        }
        // Phase C: weight by wns (j = 2t + (h4>>1), same for all reg) and reduce over 16 r-lanes
        float osum[16];
        #pragma unroll
        for (int t = 0; t < 4; ++t) {
            float wv = wns2[ptW][(2*t + (h4 >> 1))*32 + hRow];
            #pragma unroll
            for (int reg = 0; reg < 4; ++reg) osum[t*4+reg] = acc[t][reg] * wv;
        }
        #pragma unroll
        for (int s = 0; s < 16; ++s) {
            #pragma unroll
            for (int msk = 1; msk <= 8; msk <<= 1)
                osum[s] += __shfl_xor(osum[s], msk);
        }
        if (r == 0) {
            #pragma unroll
            for (int s = 0; s < 16; ++s) redO[w*4+h4][s] = osum[s];
        }
        __syncthreads();
        // Phase D: combine the two waves of each point, write out
        if (tid < 128) {
            int pt = tid >> 6, i2 = tid & 63;
            int t = i2 >> 4, hh = (i2 >> 2) & 3, reg = i2 & 3, s = t*4 + reg;
            float val = redO[(pt*2)*4 + hh][s] + redO[(pt*2+1)*4 + hh][s];
            out[(size_t)(m0 + pt)*64 + 16*t + 4*hh + reg] = val;
        }
        __syncthreads();
    }
}

extern "C" void kernel_launch(void* const* d_in, const int* in_sizes, int n_in,
                              void* d_out, int out_size, void* d_ws, size_t ws_size,
                              hipStream_t stream) {
    const float* q_pts   = (const float*)d_in[0];
    const float* s_pts   = (const float*)d_in[1];
    const float* s_feats = (const float*)d_in[2];
    const int*   inds    = (const int*)d_in[3];
    const float* dW1 = (const float*)d_in[4];
    const float* dbg = (const float*)d_in[5];
    const float* dbb = (const float*)d_in[6];
    const float* dW2 = (const float*)d_in[7];
    const float* db2 = (const float*)d_in[8];
    const float* gng = (const float*)d_in[9];
    const float* gnb = (const float*)d_in[10];
    const float* gW  = (const float*)d_in[11];
    const float* gb  = (const float*)d_in[12];
    const float* ang = (const float*)d_in[13];
    const float* anb = (const float*)d_in[14];
    const float* aW1 = (const float*)d_in[15];
    const float* abg = (const float*)d_in[16];
    const float* abb = (const float*)d_in[17];
    const float* aW2 = (const float*)d_in[18];
    const float* ab2 = (const float*)d_in[19];
    float* out = (float*)d_out;

    char* ws = (char*)d_ws;
    float* part1 = (float*)ws;                           // 64KB
    float* partS = (float*)(ws + (1<<20));               // 1MB
    float* st1   = (float*)(ws + (2<<20));
    float* st2 = st1 + 128;
    float* st3 = st1 + 256;
    float* st4 = st1 + 384;
    float* v20  = (float*)(ws + (3<<20));                // 12.8MB
    const size_t szG = (size_t)MHt * 64 * 2;             // 204.8MB bf16

    bf16*  geom = (bf16*)(ws + ((size_t)16<<20));
    unsigned short* geomU = (unsigned short*)geom;
    __half* wnsG = (__half*)(ws + ((size_t)16<<20) + szG);
    const size_t needE2 = ((size_t)16<<20) + szG + (size_t)Mq*256*2;  // ~246.4MB (validated present)

    if (ws_size < needE2) return;

    k1_moments<<<GRID_K1, 256, 0, stream>>>(q_pts, s_pts, inds, part1);
    kfin1<<<1, 1024, 0, stream>>>(part1, dW1, dbg, dbb, st1);
    k2m<<<GRID_SWEEP, 256, 0, stream>>>(q_pts, s_pts, s_feats, inds, dW1, st1, dW2, db2, geomU, partS);
    kfinS<<<1, 1024, 0, stream>>>(partS, gng, gnb, st2);
    k3e<<<GRID_SWEEP, 256, 0, stream>>>(s_feats, inds, geom, st2, gW, gb, v20, partS);
    kfinS<<<1, 1024, 0, stream>>>(partS, ang, anb, st3);
    k4m<<<GRID_SWEEP, 256, 0, stream>>>(geomU, v20, st3, aW1, partS);
    kfinS<<<1, 1024, 0, stream>>>(partS, abg, abb, st4);
    k5wm<<<GRID_SWEEP, 256, 0, stream>>>(geomU, v20, st3, aW1, st4, aW2, ab2, wnsG);
    k6m<<<GRID_SWEEP, 256, 0, stream>>>(s_feats, inds, geomU, st2, gW, gb, wnsG, out);
}